// Round 11
// baseline (912.946 us; speedup 1.0000x reference)
//
#include <hip/hip_runtime.h>

static constexpr int NNODE = 98304;
static constexpr int NEDGE = 393216;
static constexpr int NB    = 4096;
static constexpr int CAP   = 32;

typedef __attribute__((ext_vector_type(8))) short  short8;
typedef __attribute__((ext_vector_type(8))) unsigned short ushort8;
typedef __attribute__((ext_vector_type(4))) float  f32x4;

__device__ inline unsigned short f2bf(float x) {
    unsigned int u = __float_as_uint(x);
    u += 0x7fffu + ((u >> 16) & 1u);
    return (unsigned short)(u >> 16);
}
__device__ inline float bf2f(unsigned short h) {
    return __uint_as_float(((unsigned int)h) << 16);
}

// weight planes: transposed [Npad][K32]; node weights padded to NT*64 cols
static constexpr int OW1 = 0,         NW1 = 128 * 96;
static constexpr int OW2 = OW1 + NW1, NW2 = 192 * 96;
static constexpr int OW3 = OW2 + NW2, NW3 = 320 * 160;
static constexpr int OG1 = OW3 + NW3, NG1 = 1024 * 320;
static constexpr int OG2 = OG1 + NG1, NG2 = 128 * 1024;
static constexpr int OD1 = OG2 + NG2, ND1 = 512 * 800;
static constexpr int OD2 = OD1 + ND1, ND2 = 256 * 512;
static constexpr int OD3 = OD2 + ND2, ND3 = 128 * 256;
static constexpr int OF1 = OD3 + ND3, NF1 = 1024 * 256;
static constexpr int OF2 = OF1 + NF1, NF2 = 512 * 1024;
static constexpr int WTOT = OF2 + NF2;

// ============================ graph preprocessing ============================

__global__ void k_zeroi(int* p, int n) {
    int i = blockIdx.x * blockDim.x + threadIdx.x;
    if (i < n) p[i] = 0;
}
__global__ void k_fillv(float* p, float v, int n) {
    int i = blockIdx.x * blockDim.x + threadIdx.x;
    if (i < n) p[i] = v;
}
__global__ void k_counti(const int* __restrict__ dst, int* cnt, int e) {
    int i = blockIdx.x * blockDim.x + threadIdx.x;
    if (i < e) atomicAdd(&cnt[dst[i]], 1);
}
__global__ void k_dinv(const int* __restrict__ cnt, float* dinv, int n) {
    int i = blockIdx.x * blockDim.x + threadIdx.x;
    if (i < n) dinv[i] = rsqrtf(1.0f + (float)cnt[i]);
}
__global__ void k_bucket(const int* __restrict__ src, const int* __restrict__ dst,
                         const float* __restrict__ dinv, int* pos,
                         int* __restrict__ bsrc, float* __restrict__ bnrm, int e) {
    int i = blockIdx.x * blockDim.x + threadIdx.x;
    if (i >= e) return;
    int s = src[i], d = dst[i];
    int p = atomicAdd(&pos[d], 1);
    if (p < CAP) {
        bsrc[(size_t)d * CAP + p] = s;
        bnrm[(size_t)d * CAP + p] = dinv[s] * dinv[d];
    }
}
// DETERMINISM (R7): canonicalize bucket order -> bitwise-stable gather sums.
__global__ void k_sortbk(const int* __restrict__ cnt, int* __restrict__ bsrc,
                         float* __restrict__ bnrm, int n) {
    int node = blockIdx.x * blockDim.x + threadIdx.x;
    if (node >= n) return;
    int deg = min(cnt[node], CAP);
    size_t base = (size_t)node * CAP;
    for (int i = 1; i < deg; ++i) {
        int s = bsrc[base + i];
        float v = bnrm[base + i];
        int j = i - 1;
        while (j >= 0 && bsrc[base + j] > s) {
            bsrc[base + j + 1] = bsrc[base + j];
            bnrm[base + j + 1] = bnrm[base + j];
            --j;
        }
        bsrc[base + j + 1] = s;
        bnrm[base + j + 1] = v;
    }
}

// ========================= weight split prepass =============================
struct SJob  { const float* src; int K, N, Npad, K32, off; };
struct SJobs { SJob j[10]; };

__global__ void k_splitw(SJobs js, unsigned short* __restrict__ WH,
                         unsigned short* __restrict__ WL) {
    int tid = blockIdx.x * blockDim.x + threadIdx.x;
    int stride = gridDim.x * blockDim.x;
    #pragma unroll 1
    for (int w = 0; w < 10; ++w) {
        SJob jb = js.j[w];
        int tot = jb.Npad * jb.K32;
        for (int i = tid; i < tot; i += stride) {
            int n = i / jb.K32, k = i - n * jb.K32;
            float x = (k < jb.K && n < jb.N) ? jb.src[(size_t)k * jb.N + n] : 0.0f;
            unsigned short h = f2bf(x);
            WH[jb.off + i] = h;
            WL[jb.off + i] = f2bf(x - bf2f(h));
        }
    }
}

// ===================== gather -> bf16 hi/lo planes ==========================
template<int DIM, int KS>
__global__ void k_gather_sp(const float* __restrict__ t, const int* __restrict__ cnt,
                            const int* __restrict__ bsrc, const float* __restrict__ bnrm,
                            const float* __restrict__ dinv,
                            unsigned short* __restrict__ Ph,
                            unsigned short* __restrict__ Pl, int n) {
    constexpr int H = KS / 2;
    int i = blockIdx.x * blockDim.x + threadIdx.x;
    if (i >= n * H) return;
    int node = i / H;
    int c2 = (i - node * H) * 2;
    size_t o = (size_t)node * KS + c2;
    if (c2 >= DIM) {
        *(unsigned int*)&Ph[o] = 0u;
        *(unsigned int*)&Pl[o] = 0u;
        return;
    }
    float di = dinv[node];
    float2 tv = *(const float2*)&t[(size_t)node * DIM + c2];
    float sx = tv.x * di * di, sy = tv.y * di * di;
    int deg = min(cnt[node], CAP);
    size_t base = (size_t)node * CAP;
    for (int j = 0; j < deg; ++j) {
        int s = bsrc[base + j];
        float nrm = bnrm[base + j];
        float2 v = *(const float2*)&t[(size_t)s * DIM + c2];
        sx += v.x * nrm;
        sy += v.y * nrm;
    }
    unsigned short hx = f2bf(sx), hy = f2bf(sy);
    unsigned short lx = f2bf(sx - bf2f(hx)), ly = f2bf(sy - bf2f(hy));
    *(unsigned int*)&Ph[o] = (unsigned int)hx | ((unsigned int)hy << 16);
    *(unsigned int*)&Pl[o] = (unsigned int)lx | ((unsigned int)ly << 16);
}

// ==================== N-resident bf16x3 node GEMM ===========================
// Block = 64 rows x ALL N (NT 64-col tiles in LDS). A staged ONCE per K-step
// (fetched exactly once from HBM overall); NT*12 MFMAs per barrier pair.
// POOL: per-col-tile segment-max into gpool (batch = node/24, sorted).
template<int NT, bool POOL>
__global__ __launch_bounds__(256)
void k_gemm_nres(const unsigned short* __restrict__ Ahg, const unsigned short* __restrict__ Alg,
                 const unsigned short* __restrict__ Wth, const unsigned short* __restrict__ Wtl,
                 const float* __restrict__ bias, const int* __restrict__ batch,
                 float* __restrict__ C, int M, int N, int Kb, int ldc) {
    __shared__ __align__(16) unsigned char smraw[(1 + NT) * 10240];
    ushort (*Ah)[40] = (ushort(*)[40])(smraw);
    ushort (*Al)[40] = (ushort(*)[40])(smraw + 5120);
    ushort (*Bh)[40] = (ushort(*)[40])(smraw + 10240);
    ushort (*Bl)[40] = (ushort(*)[40])(smraw + 10240 + NT * 5120);
    __shared__ int sb[64];

    const int tid  = threadIdx.x;
    const int lane = tid & 63;
    const int wv = tid >> 6, wr = wv >> 1, wc = wv & 1;
    const int m16 = lane & 15, kg = lane >> 4;
    const int row0 = blockIdx.x * 64;
    const int mA = tid >> 2, kqA = (tid & 3) << 3;

    if (POOL && tid < 64) sb[tid] = batch[row0 + tid];

    f32x4 acc[NT][2][2];
    #pragma unroll
    for (int ct = 0; ct < NT; ++ct)
        #pragma unroll
        for (int i = 0; i < 2; ++i)
            #pragma unroll
            for (int j = 0; j < 2; ++j)
                acc[ct][i][j] = f32x4{0.f, 0.f, 0.f, 0.f};

    for (int k0 = 0; k0 < Kb; k0 += 32) {
        {   // A: pure copy (planes padded, M mult 64)
            size_t ao = (size_t)(row0 + mA) * Kb + k0 + kqA;
            *(ushort8*)&Ah[mA][kqA] = *(const ushort8*)&Ahg[ao];
            *(ushort8*)&Al[mA][kqA] = *(const ushort8*)&Alg[ao];
        }
        #pragma unroll
        for (int rep = 0; rep < NT; ++rep) {   // B: all NT col-tiles (cols padded)
            int c = rep * 64 + mA;
            size_t bo = (size_t)c * Kb + k0 + kqA;
            *(ushort8*)&Bh[c][kqA] = *(const ushort8*)&Wth[bo];
            *(ushort8*)&Bl[c][kqA] = *(const ushort8*)&Wtl[bo];
        }
        __syncthreads();

        short8 ah[2], al[2];
        #pragma unroll
        for (int i = 0; i < 2; ++i) {
            ah[i] = *(const short8*)&Ah[wr * 32 + i * 16 + m16][kg * 8];
            al[i] = *(const short8*)&Al[wr * 32 + i * 16 + m16][kg * 8];
        }
        #pragma unroll
        for (int ct = 0; ct < NT; ++ct) {
            short8 bh[2], bl[2];
            #pragma unroll
            for (int j = 0; j < 2; ++j) {
                bh[j] = *(const short8*)&Bh[ct * 64 + wc * 32 + j * 16 + m16][kg * 8];
                bl[j] = *(const short8*)&Bl[ct * 64 + wc * 32 + j * 16 + m16][kg * 8];
            }
            #pragma unroll
            for (int i = 0; i < 2; ++i)
                #pragma unroll
                for (int j = 0; j < 2; ++j) {
                    acc[ct][i][j] = __builtin_amdgcn_mfma_f32_16x16x32_bf16(ah[i], bh[j], acc[ct][i][j], 0, 0, 0);
                    acc[ct][i][j] = __builtin_amdgcn_mfma_f32_16x16x32_bf16(ah[i], bl[j], acc[ct][i][j], 0, 0, 0);
                    acc[ct][i][j] = __builtin_amdgcn_mfma_f32_16x16x32_bf16(al[i], bh[j], acc[ct][i][j], 0, 0, 0);
                }
        }
        __syncthreads();
    }

    if (!POOL) {
        // C/D: col = lane&15, row = (lane>>4)*4 + reg
        #pragma unroll
        for (int ct = 0; ct < NT; ++ct)
            #pragma unroll
            for (int i = 0; i < 2; ++i)
                #pragma unroll
                for (int r = 0; r < 4; ++r) {
                    int gr = row0 + wr * 32 + i * 16 + kg * 4 + r;
                    #pragma unroll
                    for (int j = 0; j < 2; ++j) {
                        int gn = ct * 64 + wc * 32 + j * 16 + m16;
                        if (gn < N) {
                            float v = fmaxf(acc[ct][i][j][r] + bias[gn], 0.0f);
                            C[(size_t)gr * ldc + gn] = v;
                        }
                    }
                }
    } else {
        float (*Ts)[68] = (float(*)[68])smraw;   // 17408 B; tiles dead after K loop
        #pragma unroll 1
        for (int ct = 0; ct < NT; ++ct) {
            __syncthreads();
            #pragma unroll
            for (int i = 0; i < 2; ++i)
                #pragma unroll
                for (int r = 0; r < 4; ++r) {
                    int lr = wr * 32 + i * 16 + kg * 4 + r;
                    #pragma unroll
                    for (int j = 0; j < 2; ++j) {
                        int lc = wc * 32 + j * 16 + m16;
                        int gn = ct * 64 + lc;
                        float bv = (gn < N) ? bias[gn] : 0.0f;
                        Ts[lr][lc] = fmaxf(acc[ct][i][j][r] + bv, 0.0f);
                    }
                }
            __syncthreads();
            int seg = tid >> 6, col = tid & 63;
            int gcol = ct * 64 + col;
            if (gcol < N) {
                int gb = sb[0] + seg;
                float mx = -1.0f;
                for (int r = 0; r < 64; ++r)
                    if (sb[r] == gb) mx = fmaxf(mx, Ts[r][col]);
                if (mx >= 0.0f)
                    atomicMax((int*)&C[(size_t)gb * N + gcol], __float_as_int(mx));
            }
        }
    }
}

// ===================== head GEMM (col-parallel, bf16x3) =====================
// ASPLIT: A pre-split planes [M][Kb]; else f32 A split in staging.
// OSPLIT: write output as bf16 hi/lo planes (same values as in-staging split
//         of an f32 output -> numerics identical); else f32 C.
template<bool HAS_BIAS, bool RELU, bool ASPLIT, bool OSPLIT>
__global__ __launch_bounds__(256)
void k_gemm_head(const float* __restrict__ A,
                 const unsigned short* __restrict__ Ahg, const unsigned short* __restrict__ Alg,
                 const unsigned short* __restrict__ Wth, const unsigned short* __restrict__ Wtl,
                 const float* __restrict__ bias, float* __restrict__ C,
                 unsigned short* __restrict__ CH, unsigned short* __restrict__ CL,
                 int M, int N, int K, int Kb, int ldc) {
    __shared__ __align__(16) unsigned char smraw[20480];
    ushort (*Ah)[40] = (ushort(*)[40])(smraw);
    ushort (*Al)[40] = (ushort(*)[40])(smraw + 5120);
    ushort (*Bh)[40] = (ushort(*)[40])(smraw + 10240);
    ushort (*Bl)[40] = (ushort(*)[40])(smraw + 15360);

    const int tid  = threadIdx.x;
    const int lane = tid & 63;
    const int wv = tid >> 6, wr = wv >> 1, wc = wv & 1;
    const int m16 = lane & 15, kg = lane >> 4;
    const int row0 = blockIdx.y * 64, col0 = blockIdx.x * 64;
    const int mA = tid >> 2, kqA = (tid & 3) << 3;

    f32x4 acc[2][2];
    #pragma unroll
    for (int i = 0; i < 2; ++i)
        #pragma unroll
        for (int j = 0; j < 2; ++j)
            acc[i][j] = f32x4{0.f, 0.f, 0.f, 0.f};

    for (int k0 = 0; k0 < Kb; k0 += 32) {
        if (ASPLIT) {
            size_t ao = (size_t)(row0 + mA) * Kb + k0 + kqA;
            *(ushort8*)&Ah[mA][kqA] = *(const ushort8*)&Ahg[ao];
            *(ushort8*)&Al[mA][kqA] = *(const ushort8*)&Alg[ao];
        } else {
            int gr = row0 + mA;
            const float* ap = A + (size_t)gr * K + k0 + kqA;
            ushort8 vh, vl;
            #pragma unroll
            for (int u = 0; u < 8; ++u) {
                float xv = (gr < M && (k0 + kqA + u) < K) ? ap[u] : 0.f;
                unsigned short h = f2bf(xv);
                vh[u] = h; vl[u] = f2bf(xv - bf2f(h));
            }
            *(ushort8*)&Ah[mA][kqA] = vh;
            *(ushort8*)&Al[mA][kqA] = vl;
        }
        {
            int gn = col0 + mA;
            if (gn < N) {
                size_t bo = (size_t)gn * Kb + k0 + kqA;
                *(ushort8*)&Bh[mA][kqA] = *(const ushort8*)&Wth[bo];
                *(ushort8*)&Bl[mA][kqA] = *(const ushort8*)&Wtl[bo];
            } else {
                ushort8 z = {0, 0, 0, 0, 0, 0, 0, 0};
                *(ushort8*)&Bh[mA][kqA] = z;
                *(ushort8*)&Bl[mA][kqA] = z;
            }
        }
        __syncthreads();

        short8 ah[2], al[2], bh[2], bl[2];
        #pragma unroll
        for (int i = 0; i < 2; ++i) {
            ah[i] = *(const short8*)&Ah[wr * 32 + i * 16 + m16][kg * 8];
            al[i] = *(const short8*)&Al[wr * 32 + i * 16 + m16][kg * 8];
            bh[i] = *(const short8*)&Bh[wc * 32 + i * 16 + m16][kg * 8];
            bl[i] = *(const short8*)&Bl[wc * 32 + i * 16 + m16][kg * 8];
        }
        #pragma unroll
        for (int i = 0; i < 2; ++i)
            #pragma unroll
            for (int j = 0; j < 2; ++j) {
                acc[i][j] = __builtin_amdgcn_mfma_f32_16x16x32_bf16(ah[i], bh[j], acc[i][j], 0, 0, 0);
                acc[i][j] = __builtin_amdgcn_mfma_f32_16x16x32_bf16(ah[i], bl[j], acc[i][j], 0, 0, 0);
                acc[i][j] = __builtin_amdgcn_mfma_f32_16x16x32_bf16(al[i], bh[j], acc[i][j], 0, 0, 0);
            }
        __syncthreads();
    }

    #pragma unroll
    for (int i = 0; i < 2; ++i)
        #pragma unroll
        for (int r = 0; r < 4; ++r) {
            int gr = row0 + wr * 32 + i * 16 + kg * 4 + r;
            if (gr >= M) continue;
            #pragma unroll
            for (int j = 0; j < 2; ++j) {
                int gn = col0 + wc * 32 + j * 16 + m16;
                if (gn >= N) continue;
                float v = acc[i][j][r];
                if (HAS_BIAS) v += bias[gn];
                if (RELU) v = fmaxf(v, 0.0f);
                if (OSPLIT) {
                    unsigned short h = f2bf(v);
                    CH[(size_t)gr * ldc + gn] = h;
                    CL[(size_t)gr * ldc + gn] = f2bf(v - bf2f(h));
                } else {
                    C[(size_t)gr * ldc + gn] = v;
                }
            }
        }
}

// out[m] = dot(A[m,:], w) + b
__global__ __launch_bounds__(256)
void k_rowdot(const float* __restrict__ A, const float* __restrict__ w,
              const float* __restrict__ b, float* __restrict__ out, int M, int K) {
    int wave = (blockIdx.x * blockDim.x + threadIdx.x) >> 6;
    int lane = threadIdx.x & 63;
    if (wave >= M) return;
    const float* row = A + (size_t)wave * K;
    float s = 0.0f;
    for (int k = lane; k < K; k += 64) s += row[k] * w[k];
    #pragma unroll
    for (int off = 32; off > 0; off >>= 1) s += __shfl_down(s, off, 64);
    if (lane == 0) out[wave] = s + b[0];
}

// ================================= driver ===================================

extern "C" void kernel_launch(void* const* d_in, const int* in_sizes, int n_in,
                              void* d_out, int out_size, void* d_ws, size_t ws_size,
                              hipStream_t stream) {
    const float* x      = (const float*)d_in[0];
    const int*   ei     = (const int*)d_in[1];
    const int*   batch  = (const int*)d_in[2];
    const float* target = (const float*)d_in[3];
    const float* W1  = (const float*)d_in[5],  *b1  = (const float*)d_in[6];
    const float* W2  = (const float*)d_in[7],  *b2  = (const float*)d_in[8];
    const float* W3  = (const float*)d_in[9],  *b3  = (const float*)d_in[10];
    const float* Wg1 = (const float*)d_in[11], *bg1 = (const float*)d_in[12];
    const float* Wg2 = (const float*)d_in[13], *bg2 = (const float*)d_in[14];
    const float* Wd  = (const float*)d_in[15], *bd  = (const float*)d_in[16];
    const float* Wd2 = (const float*)d_in[17], *bd2 = (const float*)d_in[18];
    const float* Wd3 = (const float*)d_in[19], *bd3 = (const float*)d_in[20];
    const float* Wf1 = (const float*)d_in[23], *bf1 = (const float*)d_in[24];
    const float* Wf2 = (const float*)d_in[25], *bf2 = (const float*)d_in[26];
    const float* Wo  = (const float*)d_in[27], *bo  = (const float*)d_in[28];
    float* out = (float*)d_out;

    const int* src = ei;
    const int* dst = ei + NEDGE;

    // ---- workspace carve-up
    char* pb = (char*)d_ws;
    auto alloc = [&](size_t bytes) { char* r = pb; pb += (bytes + 255) & ~(size_t)255; return r; };
    float* dinv = (float*)alloc((size_t)NNODE * 4);
    int*   cnt  = (int*)  alloc((size_t)NNODE * 4);
    int*   pos  = (int*)  alloc((size_t)NNODE * 4);
    int*   bsrc = (int*)  alloc((size_t)NNODE * CAP * 4);
    float* bnrm = (float*)alloc((size_t)NNODE * CAP * 4);
    unsigned short* WH = (unsigned short*)alloc((size_t)WTOT * 2);
    unsigned short* WL = (unsigned short*)alloc((size_t)WTOT * 2);
    unsigned short* Ph = (unsigned short*)alloc((size_t)NNODE * 160 * 2);
    unsigned short* Pl = (unsigned short*)alloc((size_t)NNODE * 160 * 2);
    float* Q = (float*)alloc((size_t)NNODE * 156 * 4);

    // heads: alias Q (dead after gather3) and Ph/Pl (dead after pool gemm)
    float* gpool = Q;                                           // [4096][312] f32
    unsigned short* g1H  = (unsigned short*)(gpool + (size_t)NB * 312);
    unsigned short* g1L  = g1H  + (size_t)NB * 1024;            // [4096][1024]
    unsigned short* xcH  = g1L  + (size_t)NB * 1024;            // [4096][256] concat
    unsigned short* xcL  = xcH  + (size_t)NB * 256;
    unsigned short* xt1H = xcL  + (size_t)NB * 256;             // [4096][512]
    unsigned short* xt1L = xt1H + (size_t)NB * 512;
    unsigned short* xt2H = xt1L + (size_t)NB * 512;             // [4096][256]
    unsigned short* xt2L = xt2H + (size_t)NB * 256;
    unsigned short* xc1H = (unsigned short*)Ph;                 // [4096][1024]
    unsigned short* xc1L = xc1H + (size_t)NB * 1024;
    float* xc2 = (float*)(xc1L + (size_t)NB * 1024);            // [4096][512] f32

    // ---- weight split prepass
    SJobs js = {{
        { W1,   78,   78,  128,   96, OW1 },
        { W2,   78,  156,  192,   96, OW2 },
        { W3,  156,  312,  320,  160, OW3 },
        { Wg1, 312, 1024, 1024,  320, OG1 },
        { Wg2, 1024, 128,  128, 1024, OG2 },
        { Wd,  800,  512,  512,  800, OD1 },
        { Wd2, 512,  256,  256,  512, OD2 },
        { Wd3, 256,  128,  128,  256, OD3 },
        { Wf1, 256, 1024, 1024,  256, OF1 },
        { Wf2, 1024, 512,  512, 1024, OF2 },
    }};
    k_splitw<<<512, 256, 0, stream>>>(js, WH, WL);

    // ---- CSR-bucket build + canonicalize
    k_zeroi <<<(2 * NNODE + 255) / 256, 256, 0, stream>>>(cnt, 2 * NNODE);
    k_counti<<<(NEDGE + 255) / 256, 256, 0, stream>>>(dst, cnt, NEDGE);
    k_dinv  <<<(NNODE + 255) / 256, 256, 0, stream>>>(cnt, dinv, NNODE);
    k_bucket<<<(NEDGE + 255) / 256, 256, 0, stream>>>(src, dst, dinv, pos, bsrc, bnrm, NEDGE);
    k_sortbk<<<(NNODE + 255) / 256, 256, 0, stream>>>(cnt, bsrc, bnrm, NNODE);

    // ---- layer 1
    k_gather_sp<78, 96><<<(NNODE * 48 + 255) / 256, 256, 0, stream>>>(x, cnt, bsrc, bnrm, dinv, Ph, Pl, NNODE);
    k_gemm_nres<2, false><<<NNODE / 64, 256, 0, stream>>>(Ph, Pl, WH + OW1, WL + OW1, b1, nullptr, Q, NNODE, 78, 96, 78);

    // ---- layer 2
    k_gather_sp<78, 96><<<(NNODE * 48 + 255) / 256, 256, 0, stream>>>(Q, cnt, bsrc, bnrm, dinv, Ph, Pl, NNODE);
    k_gemm_nres<3, false><<<NNODE / 64, 256, 0, stream>>>(Ph, Pl, WH + OW2, WL + OW2, b2, nullptr, Q, NNODE, 156, 96, 156);

    // ---- layer 3 + fused pool
    k_gather_sp<156, 160><<<(NNODE * 80 + 255) / 256, 256, 0, stream>>>(Q, cnt, bsrc, bnrm, dinv, Ph, Pl, NNODE);
    k_fillv<<<((NB * 312) + 255) / 256, 256, 0, stream>>>(gpool, 0.0f, NB * 312);
    k_gemm_nres<5, true><<<NNODE / 64, 256, 0, stream>>>(Ph, Pl, WH + OW3, WL + OW3, b3, batch, gpool, NNODE, 312, 160, 312);

    // ---- graph head: g1 = relu(gpool@Wg1+bg1) -> planes; xc[:128] = g1@Wg2+bg2 -> planes
    k_gemm_head<true, true, false, true><<<dim3(16, NB / 64), 256, 0, stream>>>(
        gpool, nullptr, nullptr, WH + OG1, WL + OG1, bg1, nullptr, g1H, g1L, NB, 1024, 312, 320, 1024);
    k_gemm_head<true, false, true, true><<<dim3(2, NB / 64), 256, 0, stream>>>(
        nullptr, g1H, g1L, WH + OG2, WL + OG2, bg2, nullptr, xcH, xcL, NB, 128, 1024, 1024, 256);

    // ---- target head -> xc[128:]
    k_gemm_head<true, true, false, true><<<dim3(8, NB / 64), 256, 0, stream>>>(
        target, nullptr, nullptr, WH + OD1, WL + OD1, bd, nullptr, xt1H, xt1L, NB, 512, 800, 800, 512);
    k_gemm_head<true, true, true, true><<<dim3(4, NB / 64), 256, 0, stream>>>(
        nullptr, xt1H, xt1L, WH + OD2, WL + OD2, bd2, nullptr, xt2H, xt2L, NB, 256, 512, 512, 256);
    k_gemm_head<true, false, true, true><<<dim3(2, NB / 64), 256, 0, stream>>>(
        nullptr, xt2H, xt2L, WH + OD3, WL + OD3, bd3, nullptr, xcH + 128, xcL + 128, NB, 128, 256, 256, 256);

    // ---- fused head
    k_gemm_head<true, true, true, true><<<dim3(16, NB / 64), 256, 0, stream>>>(
        nullptr, xcH, xcL, WH + OF1, WL + OF1, bf1, nullptr, xc1H, xc1L, NB, 1024, 256, 256, 1024);
    k_gemm_head<true, true, true, false><<<dim3(8, NB / 64), 256, 0, stream>>>(
        nullptr, xc1H, xc1L, WH + OF2, WL + OF2, bf2, xc2, nullptr, nullptr, NB, 512, 1024, 1024, 512);

    // ---- out
    k_rowdot<<<(NB * 64) / 256, 256, 0, stream>>>(xc2, Wo, bo, out, NB, 512);
}

// Round 12
// 803.504 us; speedup vs baseline: 1.1362x; 1.1362x over previous
//
#include <hip/hip_runtime.h>

static constexpr int NNODE = 98304;
static constexpr int NEDGE = 393216;
static constexpr int NB    = 4096;
static constexpr int CAP   = 32;

typedef __attribute__((ext_vector_type(8))) short  short8;
typedef __attribute__((ext_vector_type(8))) unsigned short ushort8;
typedef __attribute__((ext_vector_type(4))) float  f32x4;

__device__ inline unsigned short f2bf(float x) {
    unsigned int u = __float_as_uint(x);
    u += 0x7fffu + ((u >> 16) & 1u);
    return (unsigned short)(u >> 16);
}
__device__ inline float bf2f(unsigned short h) {
    return __uint_as_float(((unsigned int)h) << 16);
}

// weight planes: transposed [Npad][K32]; node weights padded to NT*64 cols
static constexpr int OW1 = 0,         NW1 = 128 * 96;
static constexpr int OW2 = OW1 + NW1, NW2 = 192 * 96;
static constexpr int OW3 = OW2 + NW2, NW3 = 320 * 160;
static constexpr int OG1 = OW3 + NW3, NG1 = 1024 * 320;
static constexpr int OG2 = OG1 + NG1, NG2 = 128 * 1024;
static constexpr int OD1 = OG2 + NG2, ND1 = 512 * 800;
static constexpr int OD2 = OD1 + ND1, ND2 = 256 * 512;
static constexpr int OD3 = OD2 + ND2, ND3 = 128 * 256;
static constexpr int OF1 = OD3 + ND3, NF1 = 1024 * 256;
static constexpr int OF2 = OF1 + NF1, NF2 = 512 * 1024;
static constexpr int WTOT = OF2 + NF2;

// ============================ graph preprocessing ============================

__global__ void k_zeroi(int* p, int n) {
    int i = blockIdx.x * blockDim.x + threadIdx.x;
    if (i < n) p[i] = 0;
}
__global__ void k_fillv(float* p, float v, int n) {
    int i = blockIdx.x * blockDim.x + threadIdx.x;
    if (i < n) p[i] = v;
}
__global__ void k_counti(const int* __restrict__ dst, int* cnt, int e) {
    int i = blockIdx.x * blockDim.x + threadIdx.x;
    if (i < e) atomicAdd(&cnt[dst[i]], 1);
}
__global__ void k_dinv(const int* __restrict__ cnt, float* dinv, int n) {
    int i = blockIdx.x * blockDim.x + threadIdx.x;
    if (i < n) dinv[i] = rsqrtf(1.0f + (float)cnt[i]);
}
__global__ void k_bucket(const int* __restrict__ src, const int* __restrict__ dst,
                         const float* __restrict__ dinv, int* pos,
                         int* __restrict__ bsrc, float* __restrict__ bnrm, int e) {
    int i = blockIdx.x * blockDim.x + threadIdx.x;
    if (i >= e) return;
    int s = src[i], d = dst[i];
    int p = atomicAdd(&pos[d], 1);
    if (p < CAP) {
        bsrc[(size_t)d * CAP + p] = s;
        bnrm[(size_t)d * CAP + p] = dinv[s] * dinv[d];
    }
}
// DETERMINISM (R7): canonicalize bucket order -> bitwise-stable gather sums.
__global__ void k_sortbk(const int* __restrict__ cnt, int* __restrict__ bsrc,
                         float* __restrict__ bnrm, int n) {
    int node = blockIdx.x * blockDim.x + threadIdx.x;
    if (node >= n) return;
    int deg = min(cnt[node], CAP);
    size_t base = (size_t)node * CAP;
    for (int i = 1; i < deg; ++i) {
        int s = bsrc[base + i];
        float v = bnrm[base + i];
        int j = i - 1;
        while (j >= 0 && bsrc[base + j] > s) {
            bsrc[base + j + 1] = bsrc[base + j];
            bnrm[base + j + 1] = bnrm[base + j];
            --j;
        }
        bsrc[base + j + 1] = s;
        bnrm[base + j + 1] = v;
    }
}

// ========================= weight split prepass =============================
struct SJob  { const float* src; int K, N, Npad, K32, off; };
struct SJobs { SJob j[10]; };

__global__ void k_splitw(SJobs js, unsigned short* __restrict__ WH,
                         unsigned short* __restrict__ WL) {
    int tid = blockIdx.x * blockDim.x + threadIdx.x;
    int stride = gridDim.x * blockDim.x;
    #pragma unroll 1
    for (int w = 0; w < 10; ++w) {
        SJob jb = js.j[w];
        int tot = jb.Npad * jb.K32;
        for (int i = tid; i < tot; i += stride) {
            int n = i / jb.K32, k = i - n * jb.K32;
            float x = (k < jb.K && n < jb.N) ? jb.src[(size_t)k * jb.N + n] : 0.0f;
            unsigned short h = f2bf(x);
            WH[jb.off + i] = h;
            WL[jb.off + i] = f2bf(x - bf2f(h));
        }
    }
}

// ===================== gather -> bf16 hi/lo planes ==========================
template<int DIM, int KS>
__global__ void k_gather_sp(const float* __restrict__ t, const int* __restrict__ cnt,
                            const int* __restrict__ bsrc, const float* __restrict__ bnrm,
                            const float* __restrict__ dinv,
                            unsigned short* __restrict__ Ph,
                            unsigned short* __restrict__ Pl, int n) {
    constexpr int H = KS / 2;
    int i = blockIdx.x * blockDim.x + threadIdx.x;
    if (i >= n * H) return;
    int node = i / H;
    int c2 = (i - node * H) * 2;
    size_t o = (size_t)node * KS + c2;
    if (c2 >= DIM) {
        *(unsigned int*)&Ph[o] = 0u;
        *(unsigned int*)&Pl[o] = 0u;
        return;
    }
    float di = dinv[node];
    float2 tv = *(const float2*)&t[(size_t)node * DIM + c2];
    float sx = tv.x * di * di, sy = tv.y * di * di;
    int deg = min(cnt[node], CAP);
    size_t base = (size_t)node * CAP;
    for (int j = 0; j < deg; ++j) {
        int s = bsrc[base + j];
        float nrm = bnrm[base + j];
        float2 v = *(const float2*)&t[(size_t)s * DIM + c2];
        sx += v.x * nrm;
        sy += v.y * nrm;
    }
    unsigned short hx = f2bf(sx), hy = f2bf(sy);
    unsigned short lx = f2bf(sx - bf2f(hx)), ly = f2bf(sy - bf2f(hy));
    *(unsigned int*)&Ph[o] = (unsigned int)hx | ((unsigned int)hy << 16);
    *(unsigned int*)&Pl[o] = (unsigned int)lx | ((unsigned int)ly << 16);
}

// ==================== N-resident bf16x3 node GEMM ===========================
// Block = 64 rows x ALL N (NT 64-col tiles in LDS). A staged ONCE per K-step
// (fetched exactly once from HBM overall); NT*12 MFMAs per barrier pair.
// POOL: per-col-tile segment-max into gpool (batch = node/24, sorted).
// NOTE (R11 lesson, rule #20): ALL acc[ct] indexing must be compile-time
// static — a `#pragma unroll 1` epilogue demoted acc to scratch (WRITE_SIZE
// 6 MB -> 656 MB, 2.5x slowdown). Epilogue is now fully unrolled.
template<int NT, bool POOL>
__global__ __launch_bounds__(256)
void k_gemm_nres(const unsigned short* __restrict__ Ahg, const unsigned short* __restrict__ Alg,
                 const unsigned short* __restrict__ Wth, const unsigned short* __restrict__ Wtl,
                 const float* __restrict__ bias, const int* __restrict__ batch,
                 float* __restrict__ C, int M, int N, int Kb, int ldc) {
    __shared__ __align__(16) unsigned char smraw[(1 + NT) * 10240];
    ushort (*Ah)[40] = (ushort(*)[40])(smraw);
    ushort (*Al)[40] = (ushort(*)[40])(smraw + 5120);
    ushort (*Bh)[40] = (ushort(*)[40])(smraw + 10240);
    ushort (*Bl)[40] = (ushort(*)[40])(smraw + 10240 + NT * 5120);
    __shared__ int sb[64];

    const int tid  = threadIdx.x;
    const int lane = tid & 63;
    const int wv = tid >> 6, wr = wv >> 1, wc = wv & 1;
    const int m16 = lane & 15, kg = lane >> 4;
    const int row0 = blockIdx.x * 64;
    const int mA = tid >> 2, kqA = (tid & 3) << 3;

    if (POOL && tid < 64) sb[tid] = batch[row0 + tid];

    f32x4 acc[NT][2][2];
    #pragma unroll
    for (int ct = 0; ct < NT; ++ct)
        #pragma unroll
        for (int i = 0; i < 2; ++i)
            #pragma unroll
            for (int j = 0; j < 2; ++j)
                acc[ct][i][j] = f32x4{0.f, 0.f, 0.f, 0.f};

    for (int k0 = 0; k0 < Kb; k0 += 32) {
        {   // A: pure copy (planes padded, M mult 64)
            size_t ao = (size_t)(row0 + mA) * Kb + k0 + kqA;
            *(ushort8*)&Ah[mA][kqA] = *(const ushort8*)&Ahg[ao];
            *(ushort8*)&Al[mA][kqA] = *(const ushort8*)&Alg[ao];
        }
        #pragma unroll
        for (int rep = 0; rep < NT; ++rep) {   // B: all NT col-tiles (cols padded)
            int c = rep * 64 + mA;
            size_t bo = (size_t)c * Kb + k0 + kqA;
            *(ushort8*)&Bh[c][kqA] = *(const ushort8*)&Wth[bo];
            *(ushort8*)&Bl[c][kqA] = *(const ushort8*)&Wtl[bo];
        }
        __syncthreads();

        short8 ah[2], al[2];
        #pragma unroll
        for (int i = 0; i < 2; ++i) {
            ah[i] = *(const short8*)&Ah[wr * 32 + i * 16 + m16][kg * 8];
            al[i] = *(const short8*)&Al[wr * 32 + i * 16 + m16][kg * 8];
        }
        #pragma unroll
        for (int ct = 0; ct < NT; ++ct) {
            short8 bh[2], bl[2];
            #pragma unroll
            for (int j = 0; j < 2; ++j) {
                bh[j] = *(const short8*)&Bh[ct * 64 + wc * 32 + j * 16 + m16][kg * 8];
                bl[j] = *(const short8*)&Bl[ct * 64 + wc * 32 + j * 16 + m16][kg * 8];
            }
            #pragma unroll
            for (int i = 0; i < 2; ++i)
                #pragma unroll
                for (int j = 0; j < 2; ++j) {
                    acc[ct][i][j] = __builtin_amdgcn_mfma_f32_16x16x32_bf16(ah[i], bh[j], acc[ct][i][j], 0, 0, 0);
                    acc[ct][i][j] = __builtin_amdgcn_mfma_f32_16x16x32_bf16(ah[i], bl[j], acc[ct][i][j], 0, 0, 0);
                    acc[ct][i][j] = __builtin_amdgcn_mfma_f32_16x16x32_bf16(al[i], bh[j], acc[ct][i][j], 0, 0, 0);
                }
        }
        __syncthreads();
    }

    if (!POOL) {
        // C/D: col = lane&15, row = (lane>>4)*4 + reg
        #pragma unroll
        for (int ct = 0; ct < NT; ++ct)
            #pragma unroll
            for (int i = 0; i < 2; ++i)
                #pragma unroll
                for (int r = 0; r < 4; ++r) {
                    int gr = row0 + wr * 32 + i * 16 + kg * 4 + r;
                    #pragma unroll
                    for (int j = 0; j < 2; ++j) {
                        int gn = ct * 64 + wc * 32 + j * 16 + m16;
                        if (gn < N) {
                            float v = fmaxf(acc[ct][i][j][r] + bias[gn], 0.0f);
                            C[(size_t)gr * ldc + gn] = v;
                        }
                    }
                }
    } else {
        float (*Ts)[68] = (float(*)[68])smraw;   // 17408 B; tiles dead after K loop
        #pragma unroll              // FULL unroll: static acc indexing (rule #20)
        for (int ct = 0; ct < NT; ++ct) {
            __syncthreads();
            #pragma unroll
            for (int i = 0; i < 2; ++i)
                #pragma unroll
                for (int r = 0; r < 4; ++r) {
                    int lr = wr * 32 + i * 16 + kg * 4 + r;
                    #pragma unroll
                    for (int j = 0; j < 2; ++j) {
                        int lc = wc * 32 + j * 16 + m16;
                        int gn = ct * 64 + lc;
                        float bv = (gn < N) ? bias[gn] : 0.0f;
                        Ts[lr][lc] = fmaxf(acc[ct][i][j][r] + bv, 0.0f);
                    }
                }
            __syncthreads();
            int seg = tid >> 6, col = tid & 63;
            int gcol = ct * 64 + col;
            if (gcol < N) {
                int gb = sb[0] + seg;
                float mx = -1.0f;
                for (int r = 0; r < 64; ++r)
                    if (sb[r] == gb) mx = fmaxf(mx, Ts[r][col]);
                if (mx >= 0.0f)
                    atomicMax((int*)&C[(size_t)gb * N + gcol], __float_as_int(mx));
            }
        }
    }
}

// ===================== head GEMM (col-parallel, bf16x3) =====================
// ASPLIT: A pre-split planes [M][Kb]; else f32 A split in staging.
// OSPLIT: write output as bf16 hi/lo planes (same values as in-staging split
//         of an f32 output -> numerics identical); else f32 C.
template<bool HAS_BIAS, bool RELU, bool ASPLIT, bool OSPLIT>
__global__ __launch_bounds__(256)
void k_gemm_head(const float* __restrict__ A,
                 const unsigned short* __restrict__ Ahg, const unsigned short* __restrict__ Alg,
                 const unsigned short* __restrict__ Wth, const unsigned short* __restrict__ Wtl,
                 const float* __restrict__ bias, float* __restrict__ C,
                 unsigned short* __restrict__ CH, unsigned short* __restrict__ CL,
                 int M, int N, int K, int Kb, int ldc) {
    __shared__ __align__(16) unsigned char smraw[20480];
    ushort (*Ah)[40] = (ushort(*)[40])(smraw);
    ushort (*Al)[40] = (ushort(*)[40])(smraw + 5120);
    ushort (*Bh)[40] = (ushort(*)[40])(smraw + 10240);
    ushort (*Bl)[40] = (ushort(*)[40])(smraw + 15360);

    const int tid  = threadIdx.x;
    const int lane = tid & 63;
    const int wv = tid >> 6, wr = wv >> 1, wc = wv & 1;
    const int m16 = lane & 15, kg = lane >> 4;
    const int row0 = blockIdx.y * 64, col0 = blockIdx.x * 64;
    const int mA = tid >> 2, kqA = (tid & 3) << 3;

    f32x4 acc[2][2];
    #pragma unroll
    for (int i = 0; i < 2; ++i)
        #pragma unroll
        for (int j = 0; j < 2; ++j)
            acc[i][j] = f32x4{0.f, 0.f, 0.f, 0.f};

    for (int k0 = 0; k0 < Kb; k0 += 32) {
        if (ASPLIT) {
            size_t ao = (size_t)(row0 + mA) * Kb + k0 + kqA;
            *(ushort8*)&Ah[mA][kqA] = *(const ushort8*)&Ahg[ao];
            *(ushort8*)&Al[mA][kqA] = *(const ushort8*)&Alg[ao];
        } else {
            int gr = row0 + mA;
            const float* ap = A + (size_t)gr * K + k0 + kqA;
            ushort8 vh, vl;
            #pragma unroll
            for (int u = 0; u < 8; ++u) {
                float xv = (gr < M && (k0 + kqA + u) < K) ? ap[u] : 0.f;
                unsigned short h = f2bf(xv);
                vh[u] = h; vl[u] = f2bf(xv - bf2f(h));
            }
            *(ushort8*)&Ah[mA][kqA] = vh;
            *(ushort8*)&Al[mA][kqA] = vl;
        }
        {
            int gn = col0 + mA;
            if (gn < N) {
                size_t bo = (size_t)gn * Kb + k0 + kqA;
                *(ushort8*)&Bh[mA][kqA] = *(const ushort8*)&Wth[bo];
                *(ushort8*)&Bl[mA][kqA] = *(const ushort8*)&Wtl[bo];
            } else {
                ushort8 z = {0, 0, 0, 0, 0, 0, 0, 0};
                *(ushort8*)&Bh[mA][kqA] = z;
                *(ushort8*)&Bl[mA][kqA] = z;
            }
        }
        __syncthreads();

        short8 ah[2], al[2], bh[2], bl[2];
        #pragma unroll
        for (int i = 0; i < 2; ++i) {
            ah[i] = *(const short8*)&Ah[wr * 32 + i * 16 + m16][kg * 8];
            al[i] = *(const short8*)&Al[wr * 32 + i * 16 + m16][kg * 8];
            bh[i] = *(const short8*)&Bh[wc * 32 + i * 16 + m16][kg * 8];
            bl[i] = *(const short8*)&Bl[wc * 32 + i * 16 + m16][kg * 8];
        }
        #pragma unroll
        for (int i = 0; i < 2; ++i)
            #pragma unroll
            for (int j = 0; j < 2; ++j) {
                acc[i][j] = __builtin_amdgcn_mfma_f32_16x16x32_bf16(ah[i], bh[j], acc[i][j], 0, 0, 0);
                acc[i][j] = __builtin_amdgcn_mfma_f32_16x16x32_bf16(ah[i], bl[j], acc[i][j], 0, 0, 0);
                acc[i][j] = __builtin_amdgcn_mfma_f32_16x16x32_bf16(al[i], bh[j], acc[i][j], 0, 0, 0);
            }
        __syncthreads();
    }

    #pragma unroll
    for (int i = 0; i < 2; ++i)
        #pragma unroll
        for (int r = 0; r < 4; ++r) {
            int gr = row0 + wr * 32 + i * 16 + kg * 4 + r;
            if (gr >= M) continue;
            #pragma unroll
            for (int j = 0; j < 2; ++j) {
                int gn = col0 + wc * 32 + j * 16 + m16;
                if (gn >= N) continue;
                float v = acc[i][j][r];
                if (HAS_BIAS) v += bias[gn];
                if (RELU) v = fmaxf(v, 0.0f);
                if (OSPLIT) {
                    unsigned short h = f2bf(v);
                    CH[(size_t)gr * ldc + gn] = h;
                    CL[(size_t)gr * ldc + gn] = f2bf(v - bf2f(h));
                } else {
                    C[(size_t)gr * ldc + gn] = v;
                }
            }
        }
}

// out[m] = dot(A[m,:], w) + b
__global__ __launch_bounds__(256)
void k_rowdot(const float* __restrict__ A, const float* __restrict__ w,
              const float* __restrict__ b, float* __restrict__ out, int M, int K) {
    int wave = (blockIdx.x * blockDim.x + threadIdx.x) >> 6;
    int lane = threadIdx.x & 63;
    if (wave >= M) return;
    const float* row = A + (size_t)wave * K;
    float s = 0.0f;
    for (int k = lane; k < K; k += 64) s += row[k] * w[k];
    #pragma unroll
    for (int off = 32; off > 0; off >>= 1) s += __shfl_down(s, off, 64);
    if (lane == 0) out[wave] = s + b[0];
}

// ================================= driver ===================================

extern "C" void kernel_launch(void* const* d_in, const int* in_sizes, int n_in,
                              void* d_out, int out_size, void* d_ws, size_t ws_size,
                              hipStream_t stream) {
    const float* x      = (const float*)d_in[0];
    const int*   ei     = (const int*)d_in[1];
    const int*   batch  = (const int*)d_in[2];
    const float* target = (const float*)d_in[3];
    const float* W1  = (const float*)d_in[5],  *b1  = (const float*)d_in[6];
    const float* W2  = (const float*)d_in[7],  *b2  = (const float*)d_in[8];
    const float* W3  = (const float*)d_in[9],  *b3  = (const float*)d_in[10];
    const float* Wg1 = (const float*)d_in[11], *bg1 = (const float*)d_in[12];
    const float* Wg2 = (const float*)d_in[13], *bg2 = (const float*)d_in[14];
    const float* Wd  = (const float*)d_in[15], *bd  = (const float*)d_in[16];
    const float* Wd2 = (const float*)d_in[17], *bd2 = (const float*)d_in[18];
    const float* Wd3 = (const float*)d_in[19], *bd3 = (const float*)d_in[20];
    const float* Wf1 = (const float*)d_in[23], *bf1 = (const float*)d_in[24];
    const float* Wf2 = (const float*)d_in[25], *bf2 = (const float*)d_in[26];
    const float* Wo  = (const float*)d_in[27], *bo  = (const float*)d_in[28];
    float* out = (float*)d_out;

    const int* src = ei;
    const int* dst = ei + NEDGE;

    // ---- workspace carve-up
    char* pb = (char*)d_ws;
    auto alloc = [&](size_t bytes) { char* r = pb; pb += (bytes + 255) & ~(size_t)255; return r; };
    float* dinv = (float*)alloc((size_t)NNODE * 4);
    int*   cnt  = (int*)  alloc((size_t)NNODE * 4);
    int*   pos  = (int*)  alloc((size_t)NNODE * 4);
    int*   bsrc = (int*)  alloc((size_t)NNODE * CAP * 4);
    float* bnrm = (float*)alloc((size_t)NNODE * CAP * 4);
    unsigned short* WH = (unsigned short*)alloc((size_t)WTOT * 2);
    unsigned short* WL = (unsigned short*)alloc((size_t)WTOT * 2);
    unsigned short* Ph = (unsigned short*)alloc((size_t)NNODE * 160 * 2);
    unsigned short* Pl = (unsigned short*)alloc((size_t)NNODE * 160 * 2);
    float* Q = (float*)alloc((size_t)NNODE * 156 * 4);

    // heads: alias Q (dead after gather3) and Ph/Pl (dead after pool gemm)
    float* gpool = Q;                                           // [4096][312] f32
    unsigned short* g1H  = (unsigned short*)(gpool + (size_t)NB * 312);
    unsigned short* g1L  = g1H  + (size_t)NB * 1024;            // [4096][1024]
    unsigned short* xcH  = g1L  + (size_t)NB * 1024;            // [4096][256] concat
    unsigned short* xcL  = xcH  + (size_t)NB * 256;
    unsigned short* xt1H = xcL  + (size_t)NB * 256;             // [4096][512]
    unsigned short* xt1L = xt1H + (size_t)NB * 512;
    unsigned short* xt2H = xt1L + (size_t)NB * 512;             // [4096][256]
    unsigned short* xt2L = xt2H + (size_t)NB * 256;
    unsigned short* xc1H = (unsigned short*)Ph;                 // [4096][1024]
    unsigned short* xc1L = xc1H + (size_t)NB * 1024;
    float* xc2 = (float*)(xc1L + (size_t)NB * 1024);            // [4096][512] f32

    // ---- weight split prepass
    SJobs js = {{
        { W1,   78,   78,  128,   96, OW1 },
        { W2,   78,  156,  192,   96, OW2 },
        { W3,  156,  312,  320,  160, OW3 },
        { Wg1, 312, 1024, 1024,  320, OG1 },
        { Wg2, 1024, 128,  128, 1024, OG2 },
        { Wd,  800,  512,  512,  800, OD1 },
        { Wd2, 512,  256,  256,  512, OD2 },
        { Wd3, 256,  128,  128,  256, OD3 },
        { Wf1, 256, 1024, 1024,  256, OF1 },
        { Wf2, 1024, 512,  512, 1024, OF2 },
    }};
    k_splitw<<<512, 256, 0, stream>>>(js, WH, WL);

    // ---- CSR-bucket build + canonicalize
    k_zeroi <<<(2 * NNODE + 255) / 256, 256, 0, stream>>>(cnt, 2 * NNODE);
    k_counti<<<(NEDGE + 255) / 256, 256, 0, stream>>>(dst, cnt, NEDGE);
    k_dinv  <<<(NNODE + 255) / 256, 256, 0, stream>>>(cnt, dinv, NNODE);
    k_bucket<<<(NEDGE + 255) / 256, 256, 0, stream>>>(src, dst, dinv, pos, bsrc, bnrm, NEDGE);
    k_sortbk<<<(NNODE + 255) / 256, 256, 0, stream>>>(cnt, bsrc, bnrm, NNODE);

    // ---- layer 1
    k_gather_sp<78, 96><<<(NNODE * 48 + 255) / 256, 256, 0, stream>>>(x, cnt, bsrc, bnrm, dinv, Ph, Pl, NNODE);
    k_gemm_nres<2, false><<<NNODE / 64, 256, 0, stream>>>(Ph, Pl, WH + OW1, WL + OW1, b1, nullptr, Q, NNODE, 78, 96, 78);

    // ---- layer 2
    k_gather_sp<78, 96><<<(NNODE * 48 + 255) / 256, 256, 0, stream>>>(Q, cnt, bsrc, bnrm, dinv, Ph, Pl, NNODE);
    k_gemm_nres<3, false><<<NNODE / 64, 256, 0, stream>>>(Ph, Pl, WH + OW2, WL + OW2, b2, nullptr, Q, NNODE, 156, 96, 156);

    // ---- layer 3 + fused pool
    k_gather_sp<156, 160><<<(NNODE * 80 + 255) / 256, 256, 0, stream>>>(Q, cnt, bsrc, bnrm, dinv, Ph, Pl, NNODE);
    k_fillv<<<((NB * 312) + 255) / 256, 256, 0, stream>>>(gpool, 0.0f, NB * 312);
    k_gemm_nres<5, true><<<NNODE / 64, 256, 0, stream>>>(Ph, Pl, WH + OW3, WL + OW3, b3, batch, gpool, NNODE, 312, 160, 312);

    // ---- graph head: g1 = relu(gpool@Wg1+bg1) -> planes; xc[:128] = g1@Wg2+bg2 -> planes
    k_gemm_head<true, true, false, true><<<dim3(16, NB / 64), 256, 0, stream>>>(
        gpool, nullptr, nullptr, WH + OG1, WL + OG1, bg1, nullptr, g1H, g1L, NB, 1024, 312, 320, 1024);
    k_gemm_head<true, false, true, true><<<dim3(2, NB / 64), 256, 0, stream>>>(
        nullptr, g1H, g1L, WH + OG2, WL + OG2, bg2, nullptr, xcH, xcL, NB, 128, 1024, 1024, 256);

    // ---- target head -> xc[128:]
    k_gemm_head<true, true, false, true><<<dim3(8, NB / 64), 256, 0, stream>>>(
        target, nullptr, nullptr, WH + OD1, WL + OD1, bd, nullptr, xt1H, xt1L, NB, 512, 800, 800, 512);
    k_gemm_head<true, true, true, true><<<dim3(4, NB / 64), 256, 0, stream>>>(
        nullptr, xt1H, xt1L, WH + OD2, WL + OD2, bd2, nullptr, xt2H, xt2L, NB, 256, 512, 512, 256);
    k_gemm_head<true, false, true, true><<<dim3(2, NB / 64), 256, 0, stream>>>(
        nullptr, xt2H, xt2L, WH + OD3, WL + OD3, bd3, nullptr, xcH + 128, xcL + 128, NB, 128, 256, 256, 256);

    // ---- fused head
    k_gemm_head<true, true, true, true><<<dim3(16, NB / 64), 256, 0, stream>>>(
        nullptr, xcH, xcL, WH + OF1, WL + OF1, bf1, nullptr, xc1H, xc1L, NB, 1024, 256, 256, 1024);
    k_gemm_head<true, true, true, false><<<dim3(8, NB / 64), 256, 0, stream>>>(
        nullptr, xc1H, xc1L, WH + OF2, WL + OF2, bf2, xc2, nullptr, nullptr, NB, 512, 1024, 1024, 512);

    // ---- out
    k_rowdot<<<(NB * 64) / 256, 256, 0, stream>>>(xc2, Wo, bo, out, NB, 512);
}

// Round 15
// 777.737 us; speedup vs baseline: 1.1738x; 1.0331x over previous
//
#include <hip/hip_runtime.h>

static constexpr int NNODE = 98304;
static constexpr int NEDGE = 393216;
static constexpr int NB    = 4096;
static constexpr int CAP   = 32;

typedef __attribute__((ext_vector_type(8))) short  short8;
typedef __attribute__((ext_vector_type(8))) unsigned short ushort8;
typedef __attribute__((ext_vector_type(4))) float  f32x4;

__device__ inline unsigned short f2bf(float x) {
    unsigned int u = __float_as_uint(x);
    u += 0x7fffu + ((u >> 16) & 1u);
    return (unsigned short)(u >> 16);
}
__device__ inline float bf2f(unsigned short h) {
    return __uint_as_float(((unsigned int)h) << 16);
}

// weight planes: transposed [Npad][K32]; node weights padded to NT*64 cols
static constexpr int OW1 = 0,         NW1 = 128 * 96;
static constexpr int OW2 = OW1 + NW1, NW2 = 192 * 96;
static constexpr int OW3 = OW2 + NW2, NW3 = 320 * 160;
static constexpr int OG1 = OW3 + NW3, NG1 = 1024 * 320;
static constexpr int OG2 = OG1 + NG1, NG2 = 128 * 1024;
static constexpr int OD1 = OG2 + NG2, ND1 = 512 * 800;
static constexpr int OD2 = OD1 + ND1, ND2 = 256 * 512;
static constexpr int OD3 = OD2 + ND2, ND3 = 128 * 256;
static constexpr int OF1 = OD3 + ND3, NF1 = 1024 * 256;
static constexpr int OF2 = OF1 + NF1, NF2 = 512 * 1024;
static constexpr int WTOT = OF2 + NF2;

// ============================ graph preprocessing ============================

__global__ void k_zeroi(int* p, int n) {
    int i = blockIdx.x * blockDim.x + threadIdx.x;
    if (i < n) p[i] = 0;
}
__global__ void k_fillv(float* p, float v, int n) {
    int i = blockIdx.x * blockDim.x + threadIdx.x;
    if (i < n) p[i] = v;
}
__global__ void k_counti(const int* __restrict__ dst, int* cnt, int e) {
    int i = blockIdx.x * blockDim.x + threadIdx.x;
    if (i < e) atomicAdd(&cnt[dst[i]], 1);
}
__global__ void k_dinv(const int* __restrict__ cnt, float* dinv, int n) {
    int i = blockIdx.x * blockDim.x + threadIdx.x;
    if (i < n) dinv[i] = rsqrtf(1.0f + (float)cnt[i]);
}
__global__ void k_bucket(const int* __restrict__ src, const int* __restrict__ dst,
                         const float* __restrict__ dinv, int* pos,
                         int* __restrict__ bsrc, float* __restrict__ bnrm, int e) {
    int i = blockIdx.x * blockDim.x + threadIdx.x;
    if (i >= e) return;
    int s = src[i], d = dst[i];
    int p = atomicAdd(&pos[d], 1);
    if (p < CAP) {
        bsrc[(size_t)d * CAP + p] = s;
        bnrm[(size_t)d * CAP + p] = dinv[s] * dinv[d];
    }
}
// DETERMINISM (R7): canonicalize bucket order -> bitwise-stable gather sums.
__global__ void k_sortbk(const int* __restrict__ cnt, int* __restrict__ bsrc,
                         float* __restrict__ bnrm, int n) {
    int node = blockIdx.x * blockDim.x + threadIdx.x;
    if (node >= n) return;
    int deg = min(cnt[node], CAP);
    size_t base = (size_t)node * CAP;
    for (int i = 1; i < deg; ++i) {
        int s = bsrc[base + i];
        float v = bnrm[base + i];
        int j = i - 1;
        while (j >= 0 && bsrc[base + j] > s) {
            bsrc[base + j + 1] = bsrc[base + j];
            bnrm[base + j + 1] = bnrm[base + j];
            --j;
        }
        bsrc[base + j + 1] = s;
        bnrm[base + j + 1] = v;
    }
}

// ========================= weight split prepass =============================
struct SJob  { const float* src; int K, N, Npad, K32, off; };
struct SJobs { SJob j[10]; };

__global__ void k_splitw(SJobs js, unsigned short* __restrict__ WH,
                         unsigned short* __restrict__ WL) {
    int tid = blockIdx.x * blockDim.x + threadIdx.x;
    int stride = gridDim.x * blockDim.x;
    #pragma unroll 1
    for (int w = 0; w < 10; ++w) {
        SJob jb = js.j[w];
        int tot = jb.Npad * jb.K32;
        for (int i = tid; i < tot; i += stride) {
            int n = i / jb.K32, k = i - n * jb.K32;
            float x = (k < jb.K && n < jb.N) ? jb.src[(size_t)k * jb.N + n] : 0.0f;
            unsigned short h = f2bf(x);
            WH[jb.off + i] = h;
            WL[jb.off + i] = f2bf(x - bf2f(h));
        }
    }
}

// ===================== gather -> bf16 hi/lo planes ==========================
template<int DIM, int KS>
__global__ void k_gather_sp(const float* __restrict__ t, const int* __restrict__ cnt,
                            const int* __restrict__ bsrc, const float* __restrict__ bnrm,
                            const float* __restrict__ dinv,
                            unsigned short* __restrict__ Ph,
                            unsigned short* __restrict__ Pl, int n) {
    constexpr int H = KS / 2;
    int i = blockIdx.x * blockDim.x + threadIdx.x;
    if (i >= n * H) return;
    int node = i / H;
    int c2 = (i - node * H) * 2;
    size_t o = (size_t)node * KS + c2;
    if (c2 >= DIM) {
        *(unsigned int*)&Ph[o] = 0u;
        *(unsigned int*)&Pl[o] = 0u;
        return;
    }
    float di = dinv[node];
    float2 tv = *(const float2*)&t[(size_t)node * DIM + c2];
    float sx = tv.x * di * di, sy = tv.y * di * di;
    int deg = min(cnt[node], CAP);
    size_t base = (size_t)node * CAP;
    for (int j = 0; j < deg; ++j) {
        int s = bsrc[base + j];
        float nrm = bnrm[base + j];
        float2 v = *(const float2*)&t[(size_t)s * DIM + c2];
        sx += v.x * nrm;
        sy += v.y * nrm;
    }
    unsigned short hx = f2bf(sx), hy = f2bf(sy);
    unsigned short lx = f2bf(sx - bf2f(hx)), ly = f2bf(sy - bf2f(hy));
    *(unsigned int*)&Ph[o] = (unsigned int)hx | ((unsigned int)hy << 16);
    *(unsigned int*)&Pl[o] = (unsigned int)lx | ((unsigned int)ly << 16);
}

// ==================== N-resident bf16x3 node GEMM ===========================
// Block = 64 rows x ALL N (NT 64-col tiles in LDS). A fetched exactly once.
// R12 evidence: 256-thread version was latency-bound at 21% occupancy (62 KB
// LDS -> 2 blocks/CU x 4 waves). Now 512 threads = 8 waves (2M x 4N grid,
// wave owns 16-col slices within each 64-col tile) -> 16 waves/CU at same
// LDS. All acc indexing compile-time static (rule #20, R11 lesson).
template<int NT, bool POOL>
__global__ __launch_bounds__(512)
void k_gemm_nres(const unsigned short* __restrict__ Ahg, const unsigned short* __restrict__ Alg,
                 const unsigned short* __restrict__ Wth, const unsigned short* __restrict__ Wtl,
                 const float* __restrict__ bias, const int* __restrict__ batch,
                 float* __restrict__ C, int M, int N, int Kb, int ldc) {
    __shared__ __align__(16) unsigned char smraw[(1 + NT) * 10240];
    ushort (*Ah)[40] = (ushort(*)[40])(smraw);
    ushort (*Al)[40] = (ushort(*)[40])(smraw + 5120);
    ushort (*Bh)[40] = (ushort(*)[40])(smraw + 10240);
    ushort (*Bl)[40] = (ushort(*)[40])(smraw + 10240 + NT * 5120);
    __shared__ int sb[64];

    const int tid  = threadIdx.x;
    const int lane = tid & 63;
    const int wv = tid >> 6;                // 0..7
    const int wr = wv >> 2, wc = wv & 3;    // 2M x 4N wave grid
    const int m16 = lane & 15, kg = lane >> 4;
    const int row0 = blockIdx.x * 64;

    if (POOL && tid < 64) sb[tid] = batch[row0 + tid];

    f32x4 acc[NT][2];
    #pragma unroll
    for (int ct = 0; ct < NT; ++ct)
        #pragma unroll
        for (int i = 0; i < 2; ++i)
            acc[ct][i] = f32x4{0.f, 0.f, 0.f, 0.f};

    for (int k0 = 0; k0 < Kb; k0 += 32) {
        {   // A: 512 chunks (Ah 256 | Al 256), 1 per thread; wave-uniform plane
            int c = tid & 255;
            int row = c >> 2, ko = (c & 3) << 3;
            size_t ao = (size_t)(row0 + row) * Kb + k0 + ko;
            const unsigned short* sp = (tid < 256) ? Ahg : Alg;
            ushort (*dp)[40] = (tid < 256) ? Ah : Al;
            *(ushort8*)&dp[row][ko] = *(const ushort8*)&sp[ao];
        }
        #pragma unroll
        for (int r = 0; r < NT; ++r) {   // B: 2*NT*256 chunks; boundaries 256-aligned
            int id = r * 512 + tid;
            bool lo = id >= NT * 256;
            int cid = lo ? id - NT * 256 : id;
            int row = cid >> 2, ko = (cid & 3) << 3;
            size_t bo = (size_t)row * Kb + k0 + ko;
            const unsigned short* sp = lo ? Wtl : Wth;
            ushort (*dp)[40] = lo ? Bl : Bh;
            *(ushort8*)&dp[row][ko] = *(const ushort8*)&sp[bo];
        }
        __syncthreads();

        short8 ah[2], al[2];
        #pragma unroll
        for (int i = 0; i < 2; ++i) {
            ah[i] = *(const short8*)&Ah[wr * 32 + i * 16 + m16][kg * 8];
            al[i] = *(const short8*)&Al[wr * 32 + i * 16 + m16][kg * 8];
        }
        #pragma unroll
        for (int ct = 0; ct < NT; ++ct) {
            int c = ct * 64 + wc * 16 + m16;
            short8 bh = *(const short8*)&Bh[c][kg * 8];
            short8 bl = *(const short8*)&Bl[c][kg * 8];
            #pragma unroll
            for (int i = 0; i < 2; ++i) {
                acc[ct][i] = __builtin_amdgcn_mfma_f32_16x16x32_bf16(ah[i], bh, acc[ct][i], 0, 0, 0);
                acc[ct][i] = __builtin_amdgcn_mfma_f32_16x16x32_bf16(ah[i], bl, acc[ct][i], 0, 0, 0);
                acc[ct][i] = __builtin_amdgcn_mfma_f32_16x16x32_bf16(al[i], bh, acc[ct][i], 0, 0, 0);
            }
        }
        __syncthreads();
    }

    if (!POOL) {
        // C/D: col = lane&15, row = (lane>>4)*4 + reg
        #pragma unroll
        for (int ct = 0; ct < NT; ++ct)
            #pragma unroll
            for (int i = 0; i < 2; ++i)
                #pragma unroll
                for (int r = 0; r < 4; ++r) {
                    int gr = row0 + wr * 32 + i * 16 + kg * 4 + r;
                    int gn = ct * 64 + wc * 16 + m16;
                    if (gn < N) {
                        float v = fmaxf(acc[ct][i][r] + bias[gn], 0.0f);
                        C[(size_t)gr * ldc + gn] = v;
                    }
                }
    } else {
        float (*Ts)[68] = (float(*)[68])smraw;   // 17408 B; tiles dead after K loop
        #pragma unroll              // FULL unroll: static acc indexing (rule #20)
        for (int ct = 0; ct < NT; ++ct) {
            __syncthreads();
            #pragma unroll
            for (int i = 0; i < 2; ++i)
                #pragma unroll
                for (int r = 0; r < 4; ++r) {
                    int lr = wr * 32 + i * 16 + kg * 4 + r;
                    int lc = wc * 16 + m16;
                    int gn = ct * 64 + lc;
                    float bv = (gn < N) ? bias[gn] : 0.0f;
                    Ts[lr][lc] = fmaxf(acc[ct][i][r] + bv, 0.0f);
                }
            __syncthreads();
            if (tid < 256) {
                int seg = tid >> 6, col = tid & 63;
                int gcol = ct * 64 + col;
                if (gcol < N) {
                    int gb = sb[0] + seg;
                    float mx = -1.0f;
                    for (int r = 0; r < 64; ++r)
                        if (sb[r] == gb) mx = fmaxf(mx, Ts[r][col]);
                    if (mx >= 0.0f)
                        atomicMax((int*)&C[(size_t)gb * N + gcol], __float_as_int(mx));
                }
            }
        }
    }
}

// ===================== head GEMM (col-parallel, bf16x3) =====================
// ASPLIT: A pre-split planes [M][Kb]; else f32 A split in staging.
// OSPLIT: write output as bf16 hi/lo planes (identical values to a later
//         load-and-split -> numerics unchanged); else f32 C.
template<bool HAS_BIAS, bool RELU, bool ASPLIT, bool OSPLIT>
__global__ __launch_bounds__(256)
void k_gemm_head(const float* __restrict__ A,
                 const unsigned short* __restrict__ Ahg, const unsigned short* __restrict__ Alg,
                 const unsigned short* __restrict__ Wth, const unsigned short* __restrict__ Wtl,
                 const float* __restrict__ bias, float* __restrict__ C,
                 unsigned short* __restrict__ CH, unsigned short* __restrict__ CL,
                 int M, int N, int K, int Kb, int ldc) {
    __shared__ __align__(16) unsigned char smraw[20480];
    ushort (*Ah)[40] = (ushort(*)[40])(smraw);
    ushort (*Al)[40] = (ushort(*)[40])(smraw + 5120);
    ushort (*Bh)[40] = (ushort(*)[40])(smraw + 10240);
    ushort (*Bl)[40] = (ushort(*)[40])(smraw + 15360);

    const int tid  = threadIdx.x;
    const int lane = tid & 63;
    const int wv = tid >> 6, wr = wv >> 1, wc = wv & 1;
    const int m16 = lane & 15, kg = lane >> 4;
    const int row0 = blockIdx.y * 64, col0 = blockIdx.x * 64;
    const int mA = tid >> 2, kqA = (tid & 3) << 3;

    f32x4 acc[2][2];
    #pragma unroll
    for (int i = 0; i < 2; ++i)
        #pragma unroll
        for (int j = 0; j < 2; ++j)
            acc[i][j] = f32x4{0.f, 0.f, 0.f, 0.f};

    for (int k0 = 0; k0 < Kb; k0 += 32) {
        if (ASPLIT) {
            size_t ao = (size_t)(row0 + mA) * Kb + k0 + kqA;
            *(ushort8*)&Ah[mA][kqA] = *(const ushort8*)&Ahg[ao];
            *(ushort8*)&Al[mA][kqA] = *(const ushort8*)&Alg[ao];
        } else {
            int gr = row0 + mA;
            const float* ap = A + (size_t)gr * K + k0 + kqA;
            ushort8 vh, vl;
            #pragma unroll
            for (int u = 0; u < 8; ++u) {
                float xv = (gr < M && (k0 + kqA + u) < K) ? ap[u] : 0.f;
                unsigned short h = f2bf(xv);
                vh[u] = h; vl[u] = f2bf(xv - bf2f(h));
            }
            *(ushort8*)&Ah[mA][kqA] = vh;
            *(ushort8*)&Al[mA][kqA] = vl;
        }
        {
            int gn = col0 + mA;
            if (gn < N) {
                size_t bo = (size_t)gn * Kb + k0 + kqA;
                *(ushort8*)&Bh[mA][kqA] = *(const ushort8*)&Wth[bo];
                *(ushort8*)&Bl[mA][kqA] = *(const ushort8*)&Wtl[bo];
            } else {
                ushort8 z = {0, 0, 0, 0, 0, 0, 0, 0};
                *(ushort8*)&Bh[mA][kqA] = z;
                *(ushort8*)&Bl[mA][kqA] = z;
            }
        }
        __syncthreads();

        short8 ah[2], al[2], bh[2], bl[2];
        #pragma unroll
        for (int i = 0; i < 2; ++i) {
            ah[i] = *(const short8*)&Ah[wr * 32 + i * 16 + m16][kg * 8];
            al[i] = *(const short8*)&Al[wr * 32 + i * 16 + m16][kg * 8];
            bh[i] = *(const short8*)&Bh[wc * 32 + i * 16 + m16][kg * 8];
            bl[i] = *(const short8*)&Bl[wc * 32 + i * 16 + m16][kg * 8];
        }
        #pragma unroll
        for (int i = 0; i < 2; ++i)
            #pragma unroll
            for (int j = 0; j < 2; ++j) {
                acc[i][j] = __builtin_amdgcn_mfma_f32_16x16x32_bf16(ah[i], bh[j], acc[i][j], 0, 0, 0);
                acc[i][j] = __builtin_amdgcn_mfma_f32_16x16x32_bf16(ah[i], bl[j], acc[i][j], 0, 0, 0);
                acc[i][j] = __builtin_amdgcn_mfma_f32_16x16x32_bf16(al[i], bh[j], acc[i][j], 0, 0, 0);
            }
        __syncthreads();
    }

    #pragma unroll
    for (int i = 0; i < 2; ++i)
        #pragma unroll
        for (int r = 0; r < 4; ++r) {
            int gr = row0 + wr * 32 + i * 16 + kg * 4 + r;
            if (gr >= M) continue;
            #pragma unroll
            for (int j = 0; j < 2; ++j) {
                int gn = col0 + wc * 32 + j * 16 + m16;
                if (gn >= N) continue;
                float v = acc[i][j][r];
                if (HAS_BIAS) v += bias[gn];
                if (RELU) v = fmaxf(v, 0.0f);
                if (OSPLIT) {
                    unsigned short h = f2bf(v);
                    CH[(size_t)gr * ldc + gn] = h;
                    CL[(size_t)gr * ldc + gn] = f2bf(v - bf2f(h));
                } else {
                    C[(size_t)gr * ldc + gn] = v;
                }
            }
        }
}

// out[m] = dot(A[m,:], w) + b
__global__ __launch_bounds__(256)
void k_rowdot(const float* __restrict__ A, const float* __restrict__ w,
              const float* __restrict__ b, float* __restrict__ out, int M, int K) {
    int wave = (blockIdx.x * blockDim.x + threadIdx.x) >> 6;
    int lane = threadIdx.x & 63;
    if (wave >= M) return;
    const float* row = A + (size_t)wave * K;
    float s = 0.0f;
    for (int k = lane; k < K; k += 64) s += row[k] * w[k];
    #pragma unroll
    for (int off = 32; off > 0; off >>= 1) s += __shfl_down(s, off, 64);
    if (lane == 0) out[wave] = s + b[0];
}

// ================================= driver ===================================

extern "C" void kernel_launch(void* const* d_in, const int* in_sizes, int n_in,
                              void* d_out, int out_size, void* d_ws, size_t ws_size,
                              hipStream_t stream) {
    const float* x      = (const float*)d_in[0];
    const int*   ei     = (const int*)d_in[1];
    const int*   batch  = (const int*)d_in[2];
    const float* target = (const float*)d_in[3];
    const float* W1  = (const float*)d_in[5],  *b1  = (const float*)d_in[6];
    const float* W2  = (const float*)d_in[7],  *b2  = (const float*)d_in[8];
    const float* W3  = (const float*)d_in[9],  *b3  = (const float*)d_in[10];
    const float* Wg1 = (const float*)d_in[11], *bg1 = (const float*)d_in[12];
    const float* Wg2 = (const float*)d_in[13], *bg2 = (const float*)d_in[14];
    const float* Wd  = (const float*)d_in[15], *bd  = (const float*)d_in[16];
    const float* Wd2 = (const float*)d_in[17], *bd2 = (const float*)d_in[18];
    const float* Wd3 = (const float*)d_in[19], *bd3 = (const float*)d_in[20];
    const float* Wf1 = (const float*)d_in[23], *bf1 = (const float*)d_in[24];
    const float* Wf2 = (const float*)d_in[25], *bf2 = (const float*)d_in[26];
    const float* Wo  = (const float*)d_in[27], *bo  = (const float*)d_in[28];
    float* out = (float*)d_out;

    const int* src = ei;
    const int* dst = ei + NEDGE;

    // ---- workspace carve-up
    char* pb = (char*)d_ws;
    auto alloc = [&](size_t bytes) { char* r = pb; pb += (bytes + 255) & ~(size_t)255; return r; };
    float* dinv = (float*)alloc((size_t)NNODE * 4);
    int*   cnt  = (int*)  alloc((size_t)NNODE * 4);
    int*   pos  = (int*)  alloc((size_t)NNODE * 4);
    int*   bsrc = (int*)  alloc((size_t)NNODE * CAP * 4);
    float* bnrm = (float*)alloc((size_t)NNODE * CAP * 4);
    unsigned short* WH = (unsigned short*)alloc((size_t)WTOT * 2);
    unsigned short* WL = (unsigned short*)alloc((size_t)WTOT * 2);
    unsigned short* Ph = (unsigned short*)alloc((size_t)NNODE * 160 * 2);
    unsigned short* Pl = (unsigned short*)alloc((size_t)NNODE * 160 * 2);
    float* Q = (float*)alloc((size_t)NNODE * 156 * 4);

    // heads: alias Q (dead after gather3) and Ph/Pl (dead after pool gemm)
    float* gpool = Q;                                           // [4096][312] f32
    unsigned short* g1H  = (unsigned short*)(gpool + (size_t)NB * 312);
    unsigned short* g1L  = g1H  + (size_t)NB * 1024;            // [4096][1024]
    unsigned short* xcH  = g1L  + (size_t)NB * 1024;            // [4096][256] concat
    unsigned short* xcL  = xcH  + (size_t)NB * 256;
    unsigned short* xt1H = xcL  + (size_t)NB * 256;             // [4096][512]
    unsigned short* xt1L = xt1H + (size_t)NB * 512;
    unsigned short* xt2H = xt1L + (size_t)NB * 512;             // [4096][256]
    unsigned short* xt2L = xt2H + (size_t)NB * 256;
    unsigned short* xc1H = (unsigned short*)Ph;                 // [4096][1024]
    unsigned short* xc1L = xc1H + (size_t)NB * 1024;
    float* xc2 = (float*)(xc1L + (size_t)NB * 1024);            // [4096][512] f32

    // ---- weight split prepass
    SJobs js = {{
        { W1,   78,   78,  128,   96, OW1 },
        { W2,   78,  156,  192,   96, OW2 },
        { W3,  156,  312,  320,  160, OW3 },
        { Wg1, 312, 1024, 1024,  320, OG1 },
        { Wg2, 1024, 128,  128, 1024, OG2 },
        { Wd,  800,  512,  512,  800, OD1 },
        { Wd2, 512,  256,  256,  512, OD2 },
        { Wd3, 256,  128,  128,  256, OD3 },
        { Wf1, 256, 1024, 1024,  256, OF1 },
        { Wf2, 1024, 512,  512, 1024, OF2 },
    }};
    k_splitw<<<512, 256, 0, stream>>>(js, WH, WL);

    // ---- CSR-bucket build + canonicalize
    k_zeroi <<<(2 * NNODE + 255) / 256, 256, 0, stream>>>(cnt, 2 * NNODE);
    k_counti<<<(NEDGE + 255) / 256, 256, 0, stream>>>(dst, cnt, NEDGE);
    k_dinv  <<<(NNODE + 255) / 256, 256, 0, stream>>>(cnt, dinv, NNODE);
    k_bucket<<<(NEDGE + 255) / 256, 256, 0, stream>>>(src, dst, dinv, pos, bsrc, bnrm, NEDGE);
    k_sortbk<<<(NNODE + 255) / 256, 256, 0, stream>>>(cnt, bsrc, bnrm, NNODE);

    // ---- layer 1
    k_gather_sp<78, 96><<<(NNODE * 48 + 255) / 256, 256, 0, stream>>>(x, cnt, bsrc, bnrm, dinv, Ph, Pl, NNODE);
    k_gemm_nres<2, false><<<NNODE / 64, 512, 0, stream>>>(Ph, Pl, WH + OW1, WL + OW1, b1, nullptr, Q, NNODE, 78, 96, 78);

    // ---- layer 2
    k_gather_sp<78, 96><<<(NNODE * 48 + 255) / 256, 256, 0, stream>>>(Q, cnt, bsrc, bnrm, dinv, Ph, Pl, NNODE);
    k_gemm_nres<3, false><<<NNODE / 64, 512, 0, stream>>>(Ph, Pl, WH + OW2, WL + OW2, b2, nullptr, Q, NNODE, 156, 96, 156);

    // ---- layer 3 + fused pool
    k_gather_sp<156, 160><<<(NNODE * 80 + 255) / 256, 256, 0, stream>>>(Q, cnt, bsrc, bnrm, dinv, Ph, Pl, NNODE);
    k_fillv<<<((NB * 312) + 255) / 256, 256, 0, stream>>>(gpool, 0.0f, NB * 312);
    k_gemm_nres<5, true><<<NNODE / 64, 512, 0, stream>>>(Ph, Pl, WH + OW3, WL + OW3, b3, batch, gpool, NNODE, 312, 160, 312);

    // ---- graph head: g1 = relu(gpool@Wg1+bg1) -> planes; xc[:128] = g1@Wg2+bg2 -> planes
    k_gemm_head<true, true, false, true><<<dim3(16, NB / 64), 256, 0, stream>>>(
        gpool, nullptr, nullptr, WH + OG1, WL + OG1, bg1, nullptr, g1H, g1L, NB, 1024, 312, 320, 1024);
    k_gemm_head<true, false, true, true><<<dim3(2, NB / 64), 256, 0, stream>>>(
        nullptr, g1H, g1L, WH + OG2, WL + OG2, bg2, nullptr, xcH, xcL, NB, 128, 1024, 1024, 256);

    // ---- target head -> xc[128:]
    k_gemm_head<true, true, false, true><<<dim3(8, NB / 64), 256, 0, stream>>>(
        target, nullptr, nullptr, WH + OD1, WL + OD1, bd, nullptr, xt1H, xt1L, NB, 512, 800, 800, 512);
    k_gemm_head<true, true, true, true><<<dim3(4, NB / 64), 256, 0, stream>>>(
        nullptr, xt1H, xt1L, WH + OD2, WL + OD2, bd2, nullptr, xt2H, xt2L, NB, 256, 512, 512, 256);
    k_gemm_head<true, false, true, true><<<dim3(2, NB / 64), 256, 0, stream>>>(
        nullptr, xt2H, xt2L, WH + OD3, WL + OD3, bd3, nullptr, xcH + 128, xcL + 128, NB, 128, 256, 256, 256);

    // ---- fused head
    k_gemm_head<true, true, true, true><<<dim3(16, NB / 64), 256, 0, stream>>>(
        nullptr, xcH, xcL, WH + OF1, WL + OF1, bf1, nullptr, xc1H, xc1L, NB, 1024, 256, 256, 1024);
    k_gemm_head<true, true, true, false><<<dim3(8, NB / 64), 256, 0, stream>>>(
        nullptr, xc1H, xc1L, WH + OF2, WL + OF2, bf2, xc2, nullptr, nullptr, NB, 512, 1024, 1024, 512);

    // ---- out
    k_rowdot<<<(NB * 64) / 256, 256, 0, stream>>>(xc2, Wo, bo, out, NB, 512);
}

// Round 16
// 764.624 us; speedup vs baseline: 1.1940x; 1.0172x over previous
//
#include <hip/hip_runtime.h>

static constexpr int NNODE = 98304;
static constexpr int NEDGE = 393216;
static constexpr int NB    = 4096;
static constexpr int CAP   = 32;

typedef __attribute__((ext_vector_type(8))) short  short8;
typedef __attribute__((ext_vector_type(8))) unsigned short ushort8;
typedef __attribute__((ext_vector_type(4))) float  f32x4;

__device__ inline unsigned short f2bf(float x) {
    unsigned int u = __float_as_uint(x);
    u += 0x7fffu + ((u >> 16) & 1u);
    return (unsigned short)(u >> 16);
}
__device__ inline float bf2f(unsigned short h) {
    return __uint_as_float(((unsigned int)h) << 16);
}

// weight planes: transposed [Npad][K32]; node weights padded to tile multiples
static constexpr int OW1 = 0,         NW1 = 128 * 96;
static constexpr int OW2 = OW1 + NW1, NW2 = 192 * 96;
static constexpr int OW3 = OW2 + NW2, NW3 = 320 * 160;
static constexpr int OG1 = OW3 + NW3, NG1 = 1024 * 320;
static constexpr int OG2 = OG1 + NG1, NG2 = 128 * 1024;
static constexpr int OD1 = OG2 + NG2, ND1 = 512 * 800;
static constexpr int OD2 = OD1 + ND1, ND2 = 256 * 512;
static constexpr int OD3 = OD2 + ND2, ND3 = 128 * 256;
static constexpr int OF1 = OD3 + ND3, NF1 = 1024 * 256;
static constexpr int OF2 = OF1 + NF1, NF2 = 512 * 1024;
static constexpr int WTOT = OF2 + NF2;

// ============================ graph preprocessing ============================

__global__ void k_zeroi(int* p, int n) {
    int i = blockIdx.x * blockDim.x + threadIdx.x;
    if (i < n) p[i] = 0;
}
__global__ void k_fillv(float* p, float v, int n) {
    int i = blockIdx.x * blockDim.x + threadIdx.x;
    if (i < n) p[i] = v;
}
__global__ void k_counti(const int* __restrict__ dst, int* cnt, int e) {
    int i = blockIdx.x * blockDim.x + threadIdx.x;
    if (i < e) atomicAdd(&cnt[dst[i]], 1);
}
__global__ void k_dinv(const int* __restrict__ cnt, float* dinv, int n) {
    int i = blockIdx.x * blockDim.x + threadIdx.x;
    if (i < n) dinv[i] = rsqrtf(1.0f + (float)cnt[i]);
}
__global__ void k_bucket(const int* __restrict__ src, const int* __restrict__ dst,
                         const float* __restrict__ dinv, int* pos,
                         int* __restrict__ bsrc, float* __restrict__ bnrm, int e) {
    int i = blockIdx.x * blockDim.x + threadIdx.x;
    if (i >= e) return;
    int s = src[i], d = dst[i];
    int p = atomicAdd(&pos[d], 1);
    if (p < CAP) {
        bsrc[(size_t)d * CAP + p] = s;
        bnrm[(size_t)d * CAP + p] = dinv[s] * dinv[d];
    }
}
// DETERMINISM (R7): canonicalize bucket order -> bitwise-stable gather sums.
__global__ void k_sortbk(const int* __restrict__ cnt, int* __restrict__ bsrc,
                         float* __restrict__ bnrm, int n) {
    int node = blockIdx.x * blockDim.x + threadIdx.x;
    if (node >= n) return;
    int deg = min(cnt[node], CAP);
    size_t base = (size_t)node * CAP;
    for (int i = 1; i < deg; ++i) {
        int s = bsrc[base + i];
        float v = bnrm[base + i];
        int j = i - 1;
        while (j >= 0 && bsrc[base + j] > s) {
            bsrc[base + j + 1] = bsrc[base + j];
            bnrm[base + j + 1] = bnrm[base + j];
            --j;
        }
        bsrc[base + j + 1] = s;
        bnrm[base + j + 1] = v;
    }
}

// ========================= weight split prepass =============================
struct SJob  { const float* src; int K, N, Npad, K32, off; };
struct SJobs { SJob j[10]; };

__global__ void k_splitw(SJobs js, unsigned short* __restrict__ WH,
                         unsigned short* __restrict__ WL) {
    int tid = blockIdx.x * blockDim.x + threadIdx.x;
    int stride = gridDim.x * blockDim.x;
    #pragma unroll 1
    for (int w = 0; w < 10; ++w) {
        SJob jb = js.j[w];
        int tot = jb.Npad * jb.K32;
        for (int i = tid; i < tot; i += stride) {
            int n = i / jb.K32, k = i - n * jb.K32;
            float x = (k < jb.K && n < jb.N) ? jb.src[(size_t)k * jb.N + n] : 0.0f;
            unsigned short h = f2bf(x);
            WH[jb.off + i] = h;
            WL[jb.off + i] = f2bf(x - bf2f(h));
        }
    }
}

// ===================== gather -> bf16 hi/lo planes ==========================
template<int DIM, int KS>
__global__ void k_gather_sp(const float* __restrict__ t, const int* __restrict__ cnt,
                            const int* __restrict__ bsrc, const float* __restrict__ bnrm,
                            const float* __restrict__ dinv,
                            unsigned short* __restrict__ Ph,
                            unsigned short* __restrict__ Pl, int n) {
    constexpr int H = KS / 2;
    int i = blockIdx.x * blockDim.x + threadIdx.x;
    if (i >= n * H) return;
    int node = i / H;
    int c2 = (i - node * H) * 2;
    size_t o = (size_t)node * KS + c2;
    if (c2 >= DIM) {
        *(unsigned int*)&Ph[o] = 0u;
        *(unsigned int*)&Pl[o] = 0u;
        return;
    }
    float di = dinv[node];
    float2 tv = *(const float2*)&t[(size_t)node * DIM + c2];
    float sx = tv.x * di * di, sy = tv.y * di * di;
    int deg = min(cnt[node], CAP);
    size_t base = (size_t)node * CAP;
    for (int j = 0; j < deg; ++j) {
        int s = bsrc[base + j];
        float nrm = bnrm[base + j];
        float2 v = *(const float2*)&t[(size_t)s * DIM + c2];
        sx += v.x * nrm;
        sy += v.y * nrm;
    }
    unsigned short hx = f2bf(sx), hy = f2bf(sy);
    unsigned short lx = f2bf(sx - bf2f(hx)), ly = f2bf(sy - bf2f(hy));
    *(unsigned int*)&Ph[o] = (unsigned int)hx | ((unsigned int)hy << 16);
    *(unsigned int*)&Pl[o] = (unsigned int)lx | ((unsigned int)ly << 16);
}

// ==================== N-resident bf16x3 node GEMM ===========================
// Used ONLY for L1/L2 (NT=2,3: LDS 31/41 KB -> full 32-waves/CU occupancy).
// R15 evidence: at NT=5 (62 KB) this structure is latency-bound at ~125 us
// regardless of waves/block — the L3 pool layer reverted to col-parallel.
template<int NT, bool POOL>
__global__ __launch_bounds__(512)
void k_gemm_nres(const unsigned short* __restrict__ Ahg, const unsigned short* __restrict__ Alg,
                 const unsigned short* __restrict__ Wth, const unsigned short* __restrict__ Wtl,
                 const float* __restrict__ bias, const int* __restrict__ batch,
                 float* __restrict__ C, int M, int N, int Kb, int ldc) {
    __shared__ __align__(16) unsigned char smraw[(1 + NT) * 10240];
    ushort (*Ah)[40] = (ushort(*)[40])(smraw);
    ushort (*Al)[40] = (ushort(*)[40])(smraw + 5120);
    ushort (*Bh)[40] = (ushort(*)[40])(smraw + 10240);
    ushort (*Bl)[40] = (ushort(*)[40])(smraw + 10240 + NT * 5120);
    __shared__ int sb[64];

    const int tid  = threadIdx.x;
    const int lane = tid & 63;
    const int wv = tid >> 6;                // 0..7
    const int wr = wv >> 2, wc = wv & 3;    // 2M x 4N wave grid
    const int m16 = lane & 15, kg = lane >> 4;
    const int row0 = blockIdx.x * 64;

    if (POOL && tid < 64) sb[tid] = batch[row0 + tid];

    f32x4 acc[NT][2];
    #pragma unroll
    for (int ct = 0; ct < NT; ++ct)
        #pragma unroll
        for (int i = 0; i < 2; ++i)
            acc[ct][i] = f32x4{0.f, 0.f, 0.f, 0.f};

    for (int k0 = 0; k0 < Kb; k0 += 32) {
        {   // A: 512 chunks (Ah 256 | Al 256), 1 per thread; wave-uniform plane
            int c = tid & 255;
            int row = c >> 2, ko = (c & 3) << 3;
            size_t ao = (size_t)(row0 + row) * Kb + k0 + ko;
            const unsigned short* sp = (tid < 256) ? Ahg : Alg;
            ushort (*dp)[40] = (tid < 256) ? Ah : Al;
            *(ushort8*)&dp[row][ko] = *(const ushort8*)&sp[ao];
        }
        #pragma unroll
        for (int r = 0; r < NT; ++r) {   // B: 2*NT*256 chunks; boundaries 256-aligned
            int id = r * 512 + tid;
            bool lo = id >= NT * 256;
            int cid = lo ? id - NT * 256 : id;
            int row = cid >> 2, ko = (cid & 3) << 3;
            size_t bo = (size_t)row * Kb + k0 + ko;
            const unsigned short* sp = lo ? Wtl : Wth;
            ushort (*dp)[40] = lo ? Bl : Bh;
            *(ushort8*)&dp[row][ko] = *(const ushort8*)&sp[bo];
        }
        __syncthreads();

        short8 ah[2], al[2];
        #pragma unroll
        for (int i = 0; i < 2; ++i) {
            ah[i] = *(const short8*)&Ah[wr * 32 + i * 16 + m16][kg * 8];
            al[i] = *(const short8*)&Al[wr * 32 + i * 16 + m16][kg * 8];
        }
        #pragma unroll
        for (int ct = 0; ct < NT; ++ct) {
            int c = ct * 64 + wc * 16 + m16;
            short8 bh = *(const short8*)&Bh[c][kg * 8];
            short8 bl = *(const short8*)&Bl[c][kg * 8];
            #pragma unroll
            for (int i = 0; i < 2; ++i) {
                acc[ct][i] = __builtin_amdgcn_mfma_f32_16x16x32_bf16(ah[i], bh, acc[ct][i], 0, 0, 0);
                acc[ct][i] = __builtin_amdgcn_mfma_f32_16x16x32_bf16(ah[i], bl, acc[ct][i], 0, 0, 0);
                acc[ct][i] = __builtin_amdgcn_mfma_f32_16x16x32_bf16(al[i], bh, acc[ct][i], 0, 0, 0);
            }
        }
        __syncthreads();
    }

    // C/D: col = lane&15, row = (lane>>4)*4 + reg
    #pragma unroll
    for (int ct = 0; ct < NT; ++ct)
        #pragma unroll
        for (int i = 0; i < 2; ++i)
            #pragma unroll
            for (int r = 0; r < 4; ++r) {
                int gr = row0 + wr * 32 + i * 16 + kg * 4 + r;
                int gn = ct * 64 + wc * 16 + m16;
                if (gn < N) {
                    float v = fmaxf(acc[ct][i][r] + bias[gn], 0.0f);
                    C[(size_t)gr * ldc + gn] = v;
                }
            }
}

// ============ head / pool GEMM (col-parallel 64x64, bf16x3) =================
// ASPLIT: A pre-split planes [M][Kb]; else f32 A split in staging.
// OSPLIT: write bf16 hi/lo planes (values identical to later load+split).
// POOL (R9-proven, 95 us): fused bias/relu/segment-max into gpool via LDS
//   row-reduction (batch = node/24 sorted; 64-row tile spans <=4 graphs).
//   20.5 KB LDS @256 thr -> 8 blocks/CU: the occupancy the nres form lacks.
template<bool HAS_BIAS, bool RELU, bool ASPLIT, bool OSPLIT, bool POOL>
__global__ __launch_bounds__(256)
void k_gemm_head(const float* __restrict__ A,
                 const unsigned short* __restrict__ Ahg, const unsigned short* __restrict__ Alg,
                 const unsigned short* __restrict__ Wth, const unsigned short* __restrict__ Wtl,
                 const float* __restrict__ bias, const int* __restrict__ batch,
                 float* __restrict__ C,
                 unsigned short* __restrict__ CH, unsigned short* __restrict__ CL,
                 int M, int N, int K, int Kb, int ldc) {
    __shared__ __align__(16) unsigned char smraw[20480];
    ushort (*Ah)[40] = (ushort(*)[40])(smraw);
    ushort (*Al)[40] = (ushort(*)[40])(smraw + 5120);
    ushort (*Bh)[40] = (ushort(*)[40])(smraw + 10240);
    ushort (*Bl)[40] = (ushort(*)[40])(smraw + 15360);
    __shared__ int sb[64];

    const int tid  = threadIdx.x;
    const int lane = tid & 63;
    const int wv = tid >> 6, wr = wv >> 1, wc = wv & 1;
    const int m16 = lane & 15, kg = lane >> 4;
    const int row0 = blockIdx.y * 64, col0 = blockIdx.x * 64;
    const int mA = tid >> 2, kqA = (tid & 3) << 3;

    if (POOL && tid < 64) sb[tid] = batch[row0 + tid];   // covered by 1st barrier

    f32x4 acc[2][2];
    #pragma unroll
    for (int i = 0; i < 2; ++i)
        #pragma unroll
        for (int j = 0; j < 2; ++j)
            acc[i][j] = f32x4{0.f, 0.f, 0.f, 0.f};

    for (int k0 = 0; k0 < Kb; k0 += 32) {
        if (ASPLIT) {
            size_t ao = (size_t)(row0 + mA) * Kb + k0 + kqA;
            *(ushort8*)&Ah[mA][kqA] = *(const ushort8*)&Ahg[ao];
            *(ushort8*)&Al[mA][kqA] = *(const ushort8*)&Alg[ao];
        } else {
            int gr = row0 + mA;
            const float* ap = A + (size_t)gr * K + k0 + kqA;
            ushort8 vh, vl;
            #pragma unroll
            for (int u = 0; u < 8; ++u) {
                float xv = (gr < M && (k0 + kqA + u) < K) ? ap[u] : 0.f;
                unsigned short h = f2bf(xv);
                vh[u] = h; vl[u] = f2bf(xv - bf2f(h));
            }
            *(ushort8*)&Ah[mA][kqA] = vh;
            *(ushort8*)&Al[mA][kqA] = vl;
        }
        {
            int gn = col0 + mA;
            if (gn < N) {
                size_t bo = (size_t)gn * Kb + k0 + kqA;
                *(ushort8*)&Bh[mA][kqA] = *(const ushort8*)&Wth[bo];
                *(ushort8*)&Bl[mA][kqA] = *(const ushort8*)&Wtl[bo];
            } else {
                ushort8 z = {0, 0, 0, 0, 0, 0, 0, 0};
                *(ushort8*)&Bh[mA][kqA] = z;
                *(ushort8*)&Bl[mA][kqA] = z;
            }
        }
        __syncthreads();

        short8 ah[2], al[2], bh[2], bl[2];
        #pragma unroll
        for (int i = 0; i < 2; ++i) {
            ah[i] = *(const short8*)&Ah[wr * 32 + i * 16 + m16][kg * 8];
            al[i] = *(const short8*)&Al[wr * 32 + i * 16 + m16][kg * 8];
            bh[i] = *(const short8*)&Bh[wc * 32 + i * 16 + m16][kg * 8];
            bl[i] = *(const short8*)&Bl[wc * 32 + i * 16 + m16][kg * 8];
        }
        #pragma unroll
        for (int i = 0; i < 2; ++i)
            #pragma unroll
            for (int j = 0; j < 2; ++j) {
                acc[i][j] = __builtin_amdgcn_mfma_f32_16x16x32_bf16(ah[i], bh[j], acc[i][j], 0, 0, 0);
                acc[i][j] = __builtin_amdgcn_mfma_f32_16x16x32_bf16(ah[i], bl[j], acc[i][j], 0, 0, 0);
                acc[i][j] = __builtin_amdgcn_mfma_f32_16x16x32_bf16(al[i], bh[j], acc[i][j], 0, 0, 0);
            }
        __syncthreads();
    }

    if (POOL) {
        float (*Ts)[68] = (float(*)[68])smraw;   // 17408 <= 20480; tiles dead
        #pragma unroll
        for (int i = 0; i < 2; ++i)
            #pragma unroll
            for (int r = 0; r < 4; ++r) {
                int lr = wr * 32 + i * 16 + kg * 4 + r;
                #pragma unroll
                for (int j = 0; j < 2; ++j) {
                    int lc = wc * 32 + j * 16 + m16;
                    int gn = col0 + lc;
                    float bv = (gn < N) ? bias[gn] : 0.0f;
                    Ts[lr][lc] = fmaxf(acc[i][j][r] + bv, 0.0f);
                }
            }
        __syncthreads();
        int seg = tid >> 6, col = tid & 63;
        int gcol = col0 + col;
        if (gcol < N) {
            int gb = sb[0] + seg;
            float mx = -1.0f;
            for (int r = 0; r < 64; ++r)
                if (sb[r] == gb) mx = fmaxf(mx, Ts[r][col]);
            if (mx >= 0.0f)
                atomicMax((int*)&C[(size_t)gb * N + gcol], __float_as_int(mx));
        }
    } else {
        #pragma unroll
        for (int i = 0; i < 2; ++i)
            #pragma unroll
            for (int r = 0; r < 4; ++r) {
                int gr = row0 + wr * 32 + i * 16 + kg * 4 + r;
                if (gr >= M) continue;
                #pragma unroll
                for (int j = 0; j < 2; ++j) {
                    int gn = col0 + wc * 32 + j * 16 + m16;
                    if (gn >= N) continue;
                    float v = acc[i][j][r];
                    if (HAS_BIAS) v += bias[gn];
                    if (RELU) v = fmaxf(v, 0.0f);
                    if (OSPLIT) {
                        unsigned short h = f2bf(v);
                        CH[(size_t)gr * ldc + gn] = h;
                        CL[(size_t)gr * ldc + gn] = f2bf(v - bf2f(h));
                    } else {
                        C[(size_t)gr * ldc + gn] = v;
                    }
                }
            }
    }
}

// out[m] = dot(A[m,:], w) + b
__global__ __launch_bounds__(256)
void k_rowdot(const float* __restrict__ A, const float* __restrict__ w,
              const float* __restrict__ b, float* __restrict__ out, int M, int K) {
    int wave = (blockIdx.x * blockDim.x + threadIdx.x) >> 6;
    int lane = threadIdx.x & 63;
    if (wave >= M) return;
    const float* row = A + (size_t)wave * K;
    float s = 0.0f;
    for (int k = lane; k < K; k += 64) s += row[k] * w[k];
    #pragma unroll
    for (int off = 32; off > 0; off >>= 1) s += __shfl_down(s, off, 64);
    if (lane == 0) out[wave] = s + b[0];
}

// ================================= driver ===================================

extern "C" void kernel_launch(void* const* d_in, const int* in_sizes, int n_in,
                              void* d_out, int out_size, void* d_ws, size_t ws_size,
                              hipStream_t stream) {
    const float* x      = (const float*)d_in[0];
    const int*   ei     = (const int*)d_in[1];
    const int*   batch  = (const int*)d_in[2];
    const float* target = (const float*)d_in[3];
    const float* W1  = (const float*)d_in[5],  *b1  = (const float*)d_in[6];
    const float* W2  = (const float*)d_in[7],  *b2  = (const float*)d_in[8];
    const float* W3  = (const float*)d_in[9],  *b3  = (const float*)d_in[10];
    const float* Wg1 = (const float*)d_in[11], *bg1 = (const float*)d_in[12];
    const float* Wg2 = (const float*)d_in[13], *bg2 = (const float*)d_in[14];
    const float* Wd  = (const float*)d_in[15], *bd  = (const float*)d_in[16];
    const float* Wd2 = (const float*)d_in[17], *bd2 = (const float*)d_in[18];
    const float* Wd3 = (const float*)d_in[19], *bd3 = (const float*)d_in[20];
    const float* Wf1 = (const float*)d_in[23], *bf1 = (const float*)d_in[24];
    const float* Wf2 = (const float*)d_in[25], *bf2 = (const float*)d_in[26];
    const float* Wo  = (const float*)d_in[27], *bo  = (const float*)d_in[28];
    float* out = (float*)d_out;

    const int* src = ei;
    const int* dst = ei + NEDGE;

    // ---- workspace carve-up
    char* pb = (char*)d_ws;
    auto alloc = [&](size_t bytes) { char* r = pb; pb += (bytes + 255) & ~(size_t)255; return r; };
    float* dinv = (float*)alloc((size_t)NNODE * 4);
    int*   cnt  = (int*)  alloc((size_t)NNODE * 4);
    int*   pos  = (int*)  alloc((size_t)NNODE * 4);
    int*   bsrc = (int*)  alloc((size_t)NNODE * CAP * 4);
    float* bnrm = (float*)alloc((size_t)NNODE * CAP * 4);
    unsigned short* WH = (unsigned short*)alloc((size_t)WTOT * 2);
    unsigned short* WL = (unsigned short*)alloc((size_t)WTOT * 2);
    unsigned short* Ph = (unsigned short*)alloc((size_t)NNODE * 160 * 2);
    unsigned short* Pl = (unsigned short*)alloc((size_t)NNODE * 160 * 2);
    float* Q = (float*)alloc((size_t)NNODE * 156 * 4);

    // heads: alias Q (dead after gather3) and Ph/Pl (dead after pool gemm)
    float* gpool = Q;                                           // [4096][312] f32
    unsigned short* g1H  = (unsigned short*)(gpool + (size_t)NB * 312);
    unsigned short* g1L  = g1H  + (size_t)NB * 1024;            // [4096][1024]
    unsigned short* xcH  = g1L  + (size_t)NB * 1024;            // [4096][256] concat
    unsigned short* xcL  = xcH  + (size_t)NB * 256;
    unsigned short* xt1H = xcL  + (size_t)NB * 256;             // [4096][512]
    unsigned short* xt1L = xt1H + (size_t)NB * 512;
    unsigned short* xt2H = xt1L + (size_t)NB * 512;             // [4096][256]
    unsigned short* xt2L = xt2H + (size_t)NB * 256;
    unsigned short* xc1H = (unsigned short*)Ph;                 // [4096][1024]
    unsigned short* xc1L = xc1H + (size_t)NB * 1024;
    float* xc2 = (float*)(xc1L + (size_t)NB * 1024);            // [4096][512] f32

    // ---- weight split prepass
    SJobs js = {{
        { W1,   78,   78,  128,   96, OW1 },
        { W2,   78,  156,  192,   96, OW2 },
        { W3,  156,  312,  320,  160, OW3 },
        { Wg1, 312, 1024, 1024,  320, OG1 },
        { Wg2, 1024, 128,  128, 1024, OG2 },
        { Wd,  800,  512,  512,  800, OD1 },
        { Wd2, 512,  256,  256,  512, OD2 },
        { Wd3, 256,  128,  128,  256, OD3 },
        { Wf1, 256, 1024, 1024,  256, OF1 },
        { Wf2, 1024, 512,  512, 1024, OF2 },
    }};
    k_splitw<<<512, 256, 0, stream>>>(js, WH, WL);

    // ---- CSR-bucket build + canonicalize
    k_zeroi <<<(2 * NNODE + 255) / 256, 256, 0, stream>>>(cnt, 2 * NNODE);
    k_counti<<<(NEDGE + 255) / 256, 256, 0, stream>>>(dst, cnt, NEDGE);
    k_dinv  <<<(NNODE + 255) / 256, 256, 0, stream>>>(cnt, dinv, NNODE);
    k_bucket<<<(NEDGE + 255) / 256, 256, 0, stream>>>(src, dst, dinv, pos, bsrc, bnrm, NEDGE);
    k_sortbk<<<(NNODE + 255) / 256, 256, 0, stream>>>(cnt, bsrc, bnrm, NNODE);

    // ---- layer 1 (nres: 31 KB LDS -> full occupancy)
    k_gather_sp<78, 96><<<(NNODE * 48 + 255) / 256, 256, 0, stream>>>(x, cnt, bsrc, bnrm, dinv, Ph, Pl, NNODE);
    k_gemm_nres<2, false><<<NNODE / 64, 512, 0, stream>>>(Ph, Pl, WH + OW1, WL + OW1, b1, nullptr, Q, NNODE, 78, 96, 78);

    // ---- layer 2 (nres: 41 KB LDS)
    k_gather_sp<78, 96><<<(NNODE * 48 + 255) / 256, 256, 0, stream>>>(Q, cnt, bsrc, bnrm, dinv, Ph, Pl, NNODE);
    k_gemm_nres<3, false><<<NNODE / 64, 512, 0, stream>>>(Ph, Pl, WH + OW2, WL + OW2, b2, nullptr, Q, NNODE, 156, 96, 156);

    // ---- layer 3 + fused pool: col-parallel 64x64 (R9-proven 95 us form)
    k_gather_sp<156, 160><<<(NNODE * 80 + 255) / 256, 256, 0, stream>>>(Q, cnt, bsrc, bnrm, dinv, Ph, Pl, NNODE);
    k_fillv<<<((NB * 312) + 255) / 256, 256, 0, stream>>>(gpool, 0.0f, NB * 312);
    k_gemm_head<true, true, true, false, true><<<dim3(5, NNODE / 64), 256, 0, stream>>>(
        nullptr, Ph, Pl, WH + OW3, WL + OW3, b3, batch, gpool, nullptr, nullptr, NNODE, 312, 160, 160, 312);

    // ---- graph head: g1 = relu(gpool@Wg1+bg1) -> planes; xc[:128] = g1@Wg2+bg2 -> planes
    k_gemm_head<true, true, false, true, false><<<dim3(16, NB / 64), 256, 0, stream>>>(
        gpool, nullptr, nullptr, WH + OG1, WL + OG1, bg1, nullptr, nullptr, g1H, g1L, NB, 1024, 312, 320, 1024);
    k_gemm_head<true, false, true, true, false><<<dim3(2, NB / 64), 256, 0, stream>>>(
        nullptr, g1H, g1L, WH + OG2, WL + OG2, bg2, nullptr, nullptr, xcH, xcL, NB, 128, 1024, 1024, 256);

    // ---- target head -> xc[128:]
    k_gemm_head<true, true, false, true, false><<<dim3(8, NB / 64), 256, 0, stream>>>(
        target, nullptr, nullptr, WH + OD1, WL + OD1, bd, nullptr, nullptr, xt1H, xt1L, NB, 512, 800, 800, 512);
    k_gemm_head<true, true, true, true, false><<<dim3(4, NB / 64), 256, 0, stream>>>(
        nullptr, xt1H, xt1L, WH + OD2, WL + OD2, bd2, nullptr, nullptr, xt2H, xt2L, NB, 256, 512, 512, 256);
    k_gemm_head<true, false, true, true, false><<<dim3(2, NB / 64), 256, 0, stream>>>(
        nullptr, xt2H, xt2L, WH + OD3, WL + OD3, bd3, nullptr, nullptr, xcH + 128, xcL + 128, NB, 128, 256, 256, 256);

    // ---- fused head
    k_gemm_head<true, true, true, true, false><<<dim3(16, NB / 64), 256, 0, stream>>>(
        nullptr, xcH, xcL, WH + OF1, WL + OF1, bf1, nullptr, nullptr, xc1H, xc1L, NB, 1024, 256, 256, 1024);
    k_gemm_head<true, true, true, false, false><<<dim3(8, NB / 64), 256, 0, stream>>>(
        nullptr, xc1H, xc1L, WH + OF2, WL + OF2, bf2, nullptr, xc2, nullptr, nullptr, NB, 512, 1024, 1024, 512);

    // ---- out
    k_rowdot<<<(NB * 64) / 256, 256, 0, stream>>>(xc2, Wo, bo, out, NB, 512);
}